// Round 11
// baseline (200.274 us; speedup 1.0000x reference)
//
#include <hip/hip_runtime.h>
#include <hip/hip_bf16.h>
#include <stdint.h>

#define N 2048
#define D 128
#define H 40
#define NT 16  // 64-key tiles per k-half

typedef __attribute__((ext_vector_type(8))) short short8;
typedef __attribute__((ext_vector_type(2))) float float2v;
typedef __attribute__((ext_vector_type(4))) float float4v;
typedef __attribute__((ext_vector_type(16))) float float16v;
typedef __attribute__((ext_vector_type(2))) _Float16 half2v;

static __device__ __forceinline__ unsigned short f32_to_bf16(float f) {
  unsigned int u = __builtin_bit_cast(unsigned int, f);
  unsigned int rounding = 0x7FFFu + ((u >> 16) & 1u);
  return (unsigned short)((u + rounding) >> 16);
}

static __device__ __forceinline__ unsigned int pk2(float lo, float hi) {
  return (unsigned int)f32_to_bf16(lo) | ((unsigned int)f32_to_bf16(hi) << 16);
}

// Fast pack: round-half-up + v_perm_b32 byte gather (3 VALU). Hot path only.
static __device__ __forceinline__ unsigned int pk2f(float lo, float hi) {
  unsigned int a = __builtin_bit_cast(unsigned int, lo) + 0x8000u;
  unsigned int b = __builtin_bit_cast(unsigned int, hi) + 0x8000u;
  return __builtin_amdgcn_perm(b, a, 0x07060302u);
}

static __device__ __forceinline__ unsigned long long pack4(float x0, float x1,
                                                           float x2, float x3) {
  return (unsigned long long)pk2(x0, x1) | ((unsigned long long)pk2(x2, x3) << 32);
}

static __device__ __forceinline__ float fast_exp2(float x) {
#if __has_builtin(__builtin_amdgcn_exp2f)
  return __builtin_amdgcn_exp2f(x);
#else
  return __expf(0.69314718056f * x);
#endif
}

static __device__ __forceinline__ float bf2f(unsigned short u) {
  unsigned int x = ((unsigned int)u) << 16;
  return __builtin_bit_cast(float, x);
}

static __device__ __forceinline__ long long mk64(unsigned int lo, unsigned int hi) {
  return (long long)(((unsigned long long)hi << 32) | lo);
}

static __device__ __forceinline__ void load_lds16(const void* g, void* l) {
  __builtin_amdgcn_global_load_lds(
      (const __attribute__((address_space(1))) unsigned int*)g,
      (__attribute__((address_space(3))) unsigned int*)l, 16, 0, 0);
}

#define MFMA32(a, b, c) __builtin_amdgcn_mfma_f32_32x32x16_bf16((a), (b), (c), 0, 0, 0)
#define MFMA8(a, b, c) __builtin_amdgcn_mfma_f32_32x32x16_fp8_fp8((a), (b), (c), 0, 0, 0)

// 32x32 C-layout regs -> two bf16 B-fragments (verified R3-R10).
static __device__ __forceinline__ void regs_to_bfrags(const float16v c, int hh,
                                                      short8& f0, short8& f1) {
  unsigned int a0 = pk2f(c[0], c[1]),   a1 = pk2f(c[2], c[3]);
  unsigned int a2 = pk2f(c[4], c[5]),   a3 = pk2f(c[6], c[7]);
  unsigned int a4 = pk2f(c[8], c[9]),   a5 = pk2f(c[10], c[11]);
  unsigned int a6 = pk2f(c[12], c[13]), a7 = pk2f(c[14], c[15]);
  unsigned int x0 = __shfl_xor(hh ? a0 : a2, 32);
  unsigned int x1 = __shfl_xor(hh ? a1 : a3, 32);
  unsigned int x2 = __shfl_xor(hh ? a4 : a6, 32);
  unsigned int x3 = __shfl_xor(hh ? a5 : a7, 32);
  uint4 u0 = {hh ? x0 : a0, hh ? x1 : a1, hh ? a2 : x0, hh ? a3 : x1};
  uint4 u1 = {hh ? x2 : a4, hh ? x3 : a5, hh ? a6 : x2, hh ? a7 : x3};
  f0 = __builtin_bit_cast(short8, u0);
  f1 = __builtin_bit_cast(short8, u1);
}

// Byte-granularity version for fp8 e4m3 B-frags (Q scaled by 64). (Verified R10.)
static __device__ __forceinline__ void regs_to_f8frags(const float16v c, int hh,
                                                       long long& f0, long long& f1) {
  const float s = 64.0f;
  int v0 = __builtin_amdgcn_cvt_pk_fp8_f32(c[0] * s, c[1] * s, 0, false);
  v0 = __builtin_amdgcn_cvt_pk_fp8_f32(c[2] * s, c[3] * s, v0, true);
  int v1 = __builtin_amdgcn_cvt_pk_fp8_f32(c[4] * s, c[5] * s, 0, false);
  v1 = __builtin_amdgcn_cvt_pk_fp8_f32(c[6] * s, c[7] * s, v1, true);
  int v2 = __builtin_amdgcn_cvt_pk_fp8_f32(c[8] * s, c[9] * s, 0, false);
  v2 = __builtin_amdgcn_cvt_pk_fp8_f32(c[10] * s, c[11] * s, v2, true);
  int v3 = __builtin_amdgcn_cvt_pk_fp8_f32(c[12] * s, c[13] * s, 0, false);
  v3 = __builtin_amdgcn_cvt_pk_fp8_f32(c[14] * s, c[15] * s, v3, true);
  int t0 = __shfl_xor(hh ? v0 : v1, 32);
  int t1 = __shfl_xor(hh ? v2 : v3, 32);
  f0 = hh ? mk64((unsigned)t0, (unsigned)v1) : mk64((unsigned)v0, (unsigned)t0);
  f1 = hh ? mk64((unsigned)t1, (unsigned)v3) : mk64((unsigned)v2, (unsigned)t1);
}

// exp2(s/64), row-sum, pack bf16 P-fragments. (Verified R10.)
static __device__ __forceinline__ void regs_to_pfrags(const float16v s, int hh,
                                                      float& lsum, short8& f0,
                                                      short8& f1) {
  float e[16];
  float acc = 0.0f;
#pragma unroll
  for (int i = 0; i < 16; i++) { e[i] = fast_exp2(s[i] * 0.015625f); acc += e[i]; }
  lsum += acc;
  unsigned int a0 = pk2f(e[0], e[1]),   a1 = pk2f(e[2], e[3]);
  unsigned int a2 = pk2f(e[4], e[5]),   a3 = pk2f(e[6], e[7]);
  unsigned int a4 = pk2f(e[8], e[9]),   a5 = pk2f(e[10], e[11]);
  unsigned int a6 = pk2f(e[12], e[13]), a7 = pk2f(e[14], e[15]);
  unsigned int x0 = __shfl_xor(hh ? a0 : a2, 32);
  unsigned int x1 = __shfl_xor(hh ? a1 : a3, 32);
  unsigned int x2 = __shfl_xor(hh ? a4 : a6, 32);
  unsigned int x3 = __shfl_xor(hh ? a5 : a7, 32);
  uint4 u0 = {hh ? x0 : a0, hh ? x1 : a1, hh ? a2 : x0, hh ? a3 : x1};
  uint4 u1 = {hh ? x2 : a4, hh ? x3 : a5, hh ? a6 : x2, hh ? a7 : x3};
  f0 = __builtin_bit_cast(short8, u0);
  f1 = __builtin_bit_cast(short8, u1);
}

// ---- staging helpers for 8-wave blocks (one lane-row = 4 x 256B macro-rows) ----
static __device__ __forceinline__ void stage_64x256_w8(const char* gbase, size_t stride,
                                                       char* lds, int wave, int lane) {
#pragma unroll
  for (int i = 0; i < 2; i++) {
    int r = wave * 8 + i * 4 + (lane >> 4);
    int us = (lane & 15) ^ (r & 15);
    load_lds16(gbase + (size_t)r * stride + us * 16, lds + (wave * 8 + i * 4) * 256);
  }
}
static __device__ __forceinline__ void stage_128x256_w8(const char* gbase, size_t stride,
                                                        char* lds, int wave, int lane) {
#pragma unroll
  for (int i = 0; i < 4; i++) {
    int r = wave * 16 + i * 4 + (lane >> 4);
    int us = (lane & 15) ^ (r & 15);
    load_lds16(gbase + (size_t)r * stride + us * 16, lds + (wave * 16 + i * 4) * 256);
  }
}
// 128 bf16 rows x 128 B -> 64 macro-rows x 256 B, macro-swizzled.
static __device__ __forceinline__ void stage_128x128_w8(const char* gbase, size_t stride,
                                                        int colOff, char* lds, int wave,
                                                        int lane) {
#pragma unroll
  for (int i = 0; i < 2; i++) {
    int m = wave * 8 + i * 4 + (lane >> 4);
    int u = (lane & 15) ^ (m & 15);
    int grow = 2 * m + (u >> 3);
    load_lds16(gbase + (size_t)grow * stride + colOff + (u & 7) * 16,
               lds + (wave * 8 + i * 4) * 256);
  }
}
// 64 fp8 key-rows x 128 B -> 32 macro-rows x 256 B (8 KB).
static __device__ __forceinline__ void stage_k8_w8(const char* gbase, char* lds,
                                                   int wave, int lane) {
  int m = wave * 4 + (lane >> 4);
  int u = (lane & 15) ^ (m & 15);
  int grow = 2 * m + (u >> 3);
  load_lds16(gbase + (size_t)grow * 128 + (u & 7) * 16, lds + (wave * 4) * 256);
}
static __device__ __forceinline__ short8 read_macro(const char* lds, int row, int kunit) {
  int m = row >> 1;
  int u = ((row & 1) << 3) | kunit;
  return *(const short8*)(lds + m * 256 + ((u ^ (m & 15)) * 16));
}

// ---- fused prep: blocks 0..31 convert X (64 rows each); 32..111 convert W/V ----
__global__ __launch_bounds__(256)
void prep_kernel(const float* __restrict__ X, const float* __restrict__ W,
                 const float* __restrict__ V, unsigned short* __restrict__ Xb,
                 unsigned short* __restrict__ XbT, unsigned char* __restrict__ Xf8,
                 unsigned short* __restrict__ Wt, unsigned short* __restrict__ Vt) {
  const int tid = threadIdx.x;
  __shared__ __align__(16) unsigned short Lt[128 * 136];
  if (blockIdx.x < 32) {
    const int n0 = blockIdx.x * 64;
    for (int i = tid; i < 64 * 32; i += 256) {
      int row = i >> 5, c4 = (i & 31) * 4;
      float4v x = *(const float4v*)(X + (size_t)(n0 + row) * D + c4);
      unsigned long long p = pack4(x.x, x.y, x.z, x.w);
      *(unsigned long long*)(Lt + row * 136 + c4) = p;
      *(unsigned long long*)(Xb + (size_t)(n0 + row) * D + c4) = p;
    }
    __syncthreads();
    // XbT [d][n] (8-groups of n)
    for (int i = tid; i < 128 * 8; i += 256) {
      int d = i >> 3, g = i & 7;
      short8 v;
#pragma unroll
      for (int j = 0; j < 8; j++) v[j] = (short)Lt[(g * 8 + j) * 136 + d];
      *(short8*)(XbT + (size_t)d * N + n0 + g * 8) = v;
    }
    // Xf8 [n][d-permuted]: chunk c=2t+o holds d[32t+8o..+8) ++ d[32t+16+8o..+8)
    for (int i = tid; i < 64 * 8; i += 256) {
      int row = i >> 3, c = i & 7, t = c >> 1, o8 = (c & 1) * 8;
      const unsigned short* lp = Lt + row * 136;
      int d0 = t * 32 + o8, d1 = t * 32 + 16 + o8;
      short8 xa = *(const short8*)(lp + d0);
      short8 xb = *(const short8*)(lp + d1);
      int w0 = __builtin_amdgcn_cvt_pk_fp8_f32(bf2f(xa[0]), bf2f(xa[1]), 0, false);
      w0 = __builtin_amdgcn_cvt_pk_fp8_f32(bf2f(xa[2]), bf2f(xa[3]), w0, true);
      int w1 = __builtin_amdgcn_cvt_pk_fp8_f32(bf2f(xa[4]), bf2f(xa[5]), 0, false);
      w1 = __builtin_amdgcn_cvt_pk_fp8_f32(bf2f(xa[6]), bf2f(xa[7]), w1, true);
      int w2 = __builtin_amdgcn_cvt_pk_fp8_f32(bf2f(xb[0]), bf2f(xb[1]), 0, false);
      w2 = __builtin_amdgcn_cvt_pk_fp8_f32(bf2f(xb[2]), bf2f(xb[3]), w2, true);
      int w3 = __builtin_amdgcn_cvt_pk_fp8_f32(bf2f(xb[4]), bf2f(xb[5]), 0, false);
      w3 = __builtin_amdgcn_cvt_pk_fp8_f32(bf2f(xb[6]), bf2f(xb[7]), w3, true);
      uint4 st = {(unsigned)w0, (unsigned)w1, (unsigned)w2, (unsigned)w3};
      *(uint4*)(Xf8 + (size_t)(n0 + row) * 128 + c * 16) = st;
    }
  } else {
    const int b = blockIdx.x - 32;
    const int mat = (b >= H) ? 1 : 0;
    const int h = mat ? b - H : b;
    const float* src = (mat ? V : W) + (size_t)h * D * D;
    unsigned short* dst = (mat ? Vt : Wt) + (size_t)h * D * D;
    const float scale = mat ? 1.0f : 0.1275174313f;  // log2(e)/sqrt(128)
    for (int i = tid; i < 128 * 32; i += 256) {
      int d = i >> 5, e4 = (i & 31) * 4;
      float4v w = *(const float4v*)(src + d * D + e4);
      Lt[(e4 + 0) * 136 + d] = f32_to_bf16(w.x * scale);
      Lt[(e4 + 1) * 136 + d] = f32_to_bf16(w.y * scale);
      Lt[(e4 + 2) * 136 + d] = f32_to_bf16(w.z * scale);
      Lt[(e4 + 3) * 136 + d] = f32_to_bf16(w.w * scale);
    }
    __syncthreads();
    for (int i = tid; i < 128 * 16; i += 256) {
      int e = i >> 4, u = i & 15;
      *(uint4*)((char*)dst + (size_t)e * 256 + u * 16) =
          *(const uint4*)((const char*)Lt + (size_t)e * 272 + u * 16);
    }
  }
}

// ---- attention: 512 threads (8 waves x 32 q = 256 q), split-k x2, fp8 S ----
__global__ __launch_bounds__(512)
void attn_kernel(const unsigned short* __restrict__ Xb,
                 const unsigned char* __restrict__ Xf8,
                 const unsigned short* __restrict__ XbT,
                 const unsigned short* __restrict__ Wt,
                 const unsigned short* __restrict__ Vt,
                 unsigned short* __restrict__ Opart, float* __restrict__ Lsum) {
  __shared__ __align__(16) char smem[49152];
  char* XA = smem;            // 16K: XbT dbuf A / Vt half0 / out staging
  char* XB = smem + 16384;    // 16K: XbT dbuf B / Vt half1 / out staging
  char* KA = smem + 32768;    // 8K: fp8 K dbuf A
  char* KB = smem + 40960;    // 8K: fp8 K dbuf B
  const int bx = blockIdx.x;
  const int kh = bx & 1;
  const int q0 = ((bx >> 1) & 7) << 8;  // 256-q tile
  const int h = bx >> 4;
  const int tid = threadIdx.x;
  const int wave = tid >> 6, lane = tid & 63;
  const int l = lane & 31, hh = lane >> 5;

  const char* XbB = (const char*)Xb;
  const char* Xf8B = (const char*)Xf8;
  const char* XbTB = (const char*)XbT;
  const char* WtB = (const char*)(Wt + (size_t)h * D * D);
  const char* VtB = (const char*)(Vt + (size_t)h * D * D);
  const int kbase = kh * (N / 2);

  // 1. Wt full-stage [0,32K), K-tile0 -> KA, Q-tile A-frags straight from L2
  stage_128x256_w8(WtB, 256, smem, wave, lane);
  stage_k8_w8(Xf8B + (size_t)kbase * 128, KA, wave, lane);
  short8 xfr[8];
#pragma unroll
  for (int dk = 0; dk < 8; dk++)
    xfr[dk] = *(const short8*)(XbB + (size_t)(q0 + wave * 32 + l) * 256 + dk * 32 + hh * 16);
  __syncthreads();

  // 2. Q = Wt-frags x X-frags (per wave: its 32 q)
  float16v qa[4];
#pragma unroll
  for (int et = 0; et < 4; et++) qa[et] = (float16v)0.0f;
#pragma unroll
  for (int et = 0; et < 4; et++) {
    const int r = et * 32 + l;
#pragma unroll
    for (int dk = 0; dk < 8; dk++) {
      short8 wa = *(const short8*)(smem + r * 256 + (((2 * dk + hh) ^ (r & 15)) * 16));
      qa[et] = MFMA32(wa, xfr[dk], qa[et]);
    }
  }
  long long qf8[8];
#pragma unroll
  for (int et = 0; et < 4; et++)
    regs_to_f8frags(qa[et], hh, qf8[2 * et], qf8[2 * et + 1]);

  float16v Tacc[4];
#pragma unroll
  for (int dt = 0; dt < 4; dt++) Tacc[dt] = (float16v)0.0f;
  float lsum = 0.0f;
  __syncthreads();  // Wt reads done; [0,32K) free

  // 3. XbT tile0 -> XA
  stage_128x128_w8(XbTB, 4096, kbase * 2, XA, wave, lane);
  __syncthreads();

  // 4. main loop, double-buffered, 1 barrier/tile
  for (int kt = 0; kt < NT; kt++) {
    const char* curK = (kt & 1) ? KB : KA;
    const char* curX = (kt & 1) ? XB : XA;
    char* altK = (kt & 1) ? KA : KB;
    char* altX = (kt & 1) ? XA : XB;
    if (kt + 1 < NT) {
      const int k0n = kbase + (kt + 1) * 64;
      stage_k8_w8(Xf8B + (size_t)k0n * 128, altK, wave, lane);
      stage_128x128_w8(XbTB, 4096, k0n * 2, altX, wave, lane);
    } else {
      stage_64x256_w8(VtB, 256, altX, wave, lane);  // Vt rows 0..63 -> XA
    }
#pragma unroll
    for (int ksub = 0; ksub < 2; ksub++) {
      float16v s = (float16v)0.0f;
      const int krow = ksub * 32 + l;
      const int mb = (krow >> 1) * 256, m16 = (krow >> 1) & 15;
      const int rsel = (krow & 1) << 3;
#pragma unroll
      for (int t = 0; t < 4; t++) {
        int u = (rsel | (t * 2 + hh)) ^ m16;
        uint4 w = *(const uint4*)(curK + mb + u * 16);
        s = MFMA8(mk64(w.x, w.y), qf8[2 * t], s);
        s = MFMA8(mk64(w.z, w.w), qf8[2 * t + 1], s);
      }
      short8 pf0, pf1;
      regs_to_pfrags(s, hh, lsum, pf0, pf1);
#pragma unroll
      for (int kk = 0; kk < 2; kk++) {
        short8 pf = kk ? pf1 : pf0;
#pragma unroll
        for (int dt = 0; dt < 4; dt++) {
          short8 xt = read_macro(curX, dt * 32 + l, ksub * 4 + kk * 2 + hh);
          Tacc[dt] = MFMA32(xt, pf, Tacc[dt]);
        }
      }
    }
    __syncthreads();
  }

  float tot = lsum + __shfl_xor(lsum, 32);
  if (hh == 0) Lsum[(size_t)(h * 2 + kh) * N + q0 + wave * 32 + l] = tot;

  // 5. epilogue: O^T[e][q] = V^T[e][d] @ T^T[d][q]; Vt half1 prefetch
  stage_64x256_w8(VtB + 64 * 256, 256, XB, wave, lane);  // rows 64..127 -> XB
  short8 tb[8];
#pragma unroll
  for (int dt = 0; dt < 4; dt++)
    regs_to_bfrags(Tacc[dt], hh, tb[2 * dt], tb[2 * dt + 1]);

  float16v oacc[4];
#pragma unroll
  for (int et = 0; et < 4; et++) oacc[et] = (float16v)0.0f;
#pragma unroll
  for (int et = 0; et < 2; et++) {  // Vt half0 (XA, staged during kt=15)
    const int r = et * 32 + l;
#pragma unroll
    for (int dk = 0; dk < 8; dk++) {
      short8 va = *(const short8*)(XA + r * 256 + (((2 * dk + hh) ^ (r & 15)) * 16));
      oacc[et] = MFMA32(va, tb[dk], oacc[et]);
    }
  }
  __syncthreads();  // Vt half1 ready
#pragma unroll
  for (int et = 2; et < 4; et++) {
    const int r = (et - 2) * 32 + l;
#pragma unroll
    for (int dk = 0; dk < 8; dk++) {
      short8 va = *(const short8*)(XB + r * 256 + (((2 * dk + hh) ^ (r & 15)) * 16));
      oacc[et] = MFMA32(va, tb[dk], oacc[et]);
    }
  }

  // 6. transpose via [0,32K) in 4 passes (q-half x e-half), coalesced fp16 stores
  unsigned short* Oph = Opart + (size_t)(h * 2 + kh) * N * D;
#pragma unroll
  for (int qh = 0; qh < 2; qh++)
#pragma unroll
    for (int eh = 0; eh < 2; eh++) {
      __syncthreads();
      if ((wave >> 2) == qh) {
        const int qrow = (wave & 3) * 32 + l;
#pragma unroll
        for (int etL = 0; etL < 2; etL++) {
          int et = eh * 2 + etL;
#pragma unroll
          for (int g = 0; g < 4; g++) {
            int unit = etL * 8 + 2 * g + hh;
            float4v v;
            v.x = oacc[et][4 * g + 0];
            v.y = oacc[et][4 * g + 1];
            v.z = oacc[et][4 * g + 2];
            v.w = oacc[et][4 * g + 3];
            *(float4v*)(smem + qrow * 256 + ((unit ^ (qrow & 15)) * 16)) = v;
          }
        }
      }
      __syncthreads();
#pragma unroll
      for (int i = 0; i < 4; i++) {
        int idx = i * 512 + tid;
        int qr = idx >> 4, up = idx & 15, u = up ^ (qr & 15);
        float4v v = *(const float4v*)(smem + qr * 256 + up * 16);
        auto h0 = __builtin_amdgcn_cvt_pkrtz(v.x, v.y);
        auto h1 = __builtin_amdgcn_cvt_pkrtz(v.z, v.w);
        uint2 st = {__builtin_bit_cast(unsigned int, h0),
                    __builtin_bit_cast(unsigned int, h1)};
        *(uint2*)(Oph + (size_t)(q0 + qh * 128 + qr) * D + eh * 64 + u * 4) = st;
      }
    }
}

// ---- reduce: out[n][e] = sum_h (O[h,0]+O[h,1]) / (l[h,0]+l[h,1]) ----
__global__ __launch_bounds__(256)
void reduce_kernel(const unsigned short* __restrict__ Opart,
                   const float* __restrict__ Lsum, float* __restrict__ out) {
  int idx = blockIdx.x * 256 + threadIdx.x;  // float2 unit, 131072 total
  int n = idx >> 6;
  const unsigned int* base = (const unsigned int*)Opart;
  float2v acc = (float2v)0.0f;
#pragma unroll 8
  for (int h = 0; h < H; h++) {
    float lt = Lsum[(size_t)(2 * h) * N + n] + Lsum[(size_t)(2 * h + 1) * N + n];
    float il = __builtin_amdgcn_rcpf(lt);
    unsigned int a = base[(size_t)(2 * h) * (N * D / 2) + idx];
    unsigned int b = base[(size_t)(2 * h + 1) * (N * D / 2) + idx];
    float2v fa = __builtin_convertvector(__builtin_bit_cast(half2v, a), float2v);
    float2v fb = __builtin_convertvector(__builtin_bit_cast(half2v, b), float2v);
    acc += (fa + fb) * il;
  }
  *(float2v*)(out + (size_t)idx * 2) = acc;
}

extern "C" void kernel_launch(void* const* d_in, const int* in_sizes, int n_in,
                              void* d_out, int out_size, void* d_ws, size_t ws_size,
                              hipStream_t stream) {
  const float* X = (const float*)d_in[0];
  const float* W = (const float*)d_in[1];
  const float* V = (const float*)d_in[2];
  float* out = (float*)d_out;

  unsigned short* Xb = (unsigned short*)d_ws;        // N*D bf16
  unsigned short* XbT = Xb + (size_t)N * D;          // D*N bf16
  unsigned short* Wt = XbT + (size_t)N * D;          // H*D*D bf16 (log2e-scaled)
  unsigned short* Vt = Wt + (size_t)H * D * D;       // H*D*D bf16
  unsigned char* Xf8 = (unsigned char*)(Vt + (size_t)H * D * D);  // N*D fp8 (perm)
  unsigned short* Opart = (unsigned short*)(Xf8 + (size_t)N * D); // H*2*N*D fp16
  float* Lsum = (float*)(Opart + (size_t)H * 2 * N * D);          // H*2*N fp32

  prep_kernel<<<dim3(32 + 2 * H), 256, 0, stream>>>(X, W, V, Xb, XbT, Xf8, Wt, Vt);
  attn_kernel<<<dim3(8 * 2 * H), 512, 0, stream>>>(Xb, Xf8, XbT, Wt, Vt, Opart, Lsum);
  reduce_kernel<<<dim3(N * D / 2 / 256), 256, 0, stream>>>(Opart, Lsum, out);
}

// Round 12
// 196.195 us; speedup vs baseline: 1.0208x; 1.0208x over previous
//
#include <hip/hip_runtime.h>
#include <hip/hip_bf16.h>
#include <stdint.h>

#define N 2048
#define D 128
#define H 40
#define NT 16  // 64-key tiles per k-half

typedef __attribute__((ext_vector_type(8))) short short8;
typedef __attribute__((ext_vector_type(4))) float float4v;
typedef __attribute__((ext_vector_type(16))) float float16v;
typedef __attribute__((ext_vector_type(4))) _Float16 half4v;

static __device__ __forceinline__ unsigned short f32_to_bf16(float f) {
  unsigned int u = __builtin_bit_cast(unsigned int, f);
  unsigned int rounding = 0x7FFFu + ((u >> 16) & 1u);
  return (unsigned short)((u + rounding) >> 16);
}

static __device__ __forceinline__ unsigned int pk2(float lo, float hi) {
  return (unsigned int)f32_to_bf16(lo) | ((unsigned int)f32_to_bf16(hi) << 16);
}

// Fast pack: round-half-up + v_perm_b32 byte gather (3 VALU). Hot path only.
static __device__ __forceinline__ unsigned int pk2f(float lo, float hi) {
  unsigned int a = __builtin_bit_cast(unsigned int, lo) + 0x8000u;
  unsigned int b = __builtin_bit_cast(unsigned int, hi) + 0x8000u;
  return __builtin_amdgcn_perm(b, a, 0x07060302u);
}

static __device__ __forceinline__ unsigned long long pack4(float x0, float x1,
                                                           float x2, float x3) {
  return (unsigned long long)pk2(x0, x1) | ((unsigned long long)pk2(x2, x3) << 32);
}

static __device__ __forceinline__ float fast_exp2(float x) {
#if __has_builtin(__builtin_amdgcn_exp2f)
  return __builtin_amdgcn_exp2f(x);
#else
  return __expf(0.69314718056f * x);
#endif
}

static __device__ __forceinline__ float bf2f(unsigned short u) {
  unsigned int x = ((unsigned int)u) << 16;
  return __builtin_bit_cast(float, x);
}

static __device__ __forceinline__ long long mk64(unsigned int lo, unsigned int hi) {
  return (long long)(((unsigned long long)hi << 32) | lo);
}

static __device__ __forceinline__ void load_lds16(const void* g, void* l) {
  __builtin_amdgcn_global_load_lds(
      (const __attribute__((address_space(1))) unsigned int*)g,
      (__attribute__((address_space(3))) unsigned int*)l, 16, 0, 0);
}

#define MFMA32(a, b, c) __builtin_amdgcn_mfma_f32_32x32x16_bf16((a), (b), (c), 0, 0, 0)
#define MFMA8(a, b, c) __builtin_amdgcn_mfma_f32_32x32x16_fp8_fp8((a), (b), (c), 0, 0, 0)

// 32x32 C-layout regs -> two bf16 B-fragments (verified R3-R11).
static __device__ __forceinline__ void regs_to_bfrags(const float16v c, int hh,
                                                      short8& f0, short8& f1) {
  unsigned int a0 = pk2f(c[0], c[1]),   a1 = pk2f(c[2], c[3]);
  unsigned int a2 = pk2f(c[4], c[5]),   a3 = pk2f(c[6], c[7]);
  unsigned int a4 = pk2f(c[8], c[9]),   a5 = pk2f(c[10], c[11]);
  unsigned int a6 = pk2f(c[12], c[13]), a7 = pk2f(c[14], c[15]);
  unsigned int x0 = __shfl_xor(hh ? a0 : a2, 32);
  unsigned int x1 = __shfl_xor(hh ? a1 : a3, 32);
  unsigned int x2 = __shfl_xor(hh ? a4 : a6, 32);
  unsigned int x3 = __shfl_xor(hh ? a5 : a7, 32);
  uint4 u0 = {hh ? x0 : a0, hh ? x1 : a1, hh ? a2 : x0, hh ? a3 : x1};
  uint4 u1 = {hh ? x2 : a4, hh ? x3 : a5, hh ? a6 : x2, hh ? a7 : x3};
  f0 = __builtin_bit_cast(short8, u0);
  f1 = __builtin_bit_cast(short8, u1);
}

// Byte-granularity version for fp8 e4m3 B-frags (Q scaled by 64). (Verified R10/R11.)
static __device__ __forceinline__ void regs_to_f8frags(const float16v c, int hh,
                                                       long long& f0, long long& f1) {
  const float s = 64.0f;
  int v0 = __builtin_amdgcn_cvt_pk_fp8_f32(c[0] * s, c[1] * s, 0, false);
  v0 = __builtin_amdgcn_cvt_pk_fp8_f32(c[2] * s, c[3] * s, v0, true);
  int v1 = __builtin_amdgcn_cvt_pk_fp8_f32(c[4] * s, c[5] * s, 0, false);
  v1 = __builtin_amdgcn_cvt_pk_fp8_f32(c[6] * s, c[7] * s, v1, true);
  int v2 = __builtin_amdgcn_cvt_pk_fp8_f32(c[8] * s, c[9] * s, 0, false);
  v2 = __builtin_amdgcn_cvt_pk_fp8_f32(c[10] * s, c[11] * s, v2, true);
  int v3 = __builtin_amdgcn_cvt_pk_fp8_f32(c[12] * s, c[13] * s, 0, false);
  v3 = __builtin_amdgcn_cvt_pk_fp8_f32(c[14] * s, c[15] * s, v3, true);
  int t0 = __shfl_xor(hh ? v0 : v1, 32);
  int t1 = __shfl_xor(hh ? v2 : v3, 32);
  f0 = hh ? mk64((unsigned)t0, (unsigned)v1) : mk64((unsigned)v0, (unsigned)t0);
  f1 = hh ? mk64((unsigned)t1, (unsigned)v3) : mk64((unsigned)v2, (unsigned)t1);
}

// exp2(s/64), row-sum, pack bf16 P-fragments. (Verified R10/R11.)
static __device__ __forceinline__ void regs_to_pfrags(const float16v s, int hh,
                                                      float& lsum, short8& f0,
                                                      short8& f1) {
  float e[16];
  float acc = 0.0f;
#pragma unroll
  for (int i = 0; i < 16; i++) { e[i] = fast_exp2(s[i] * 0.015625f); acc += e[i]; }
  lsum += acc;
  unsigned int a0 = pk2f(e[0], e[1]),   a1 = pk2f(e[2], e[3]);
  unsigned int a2 = pk2f(e[4], e[5]),   a3 = pk2f(e[6], e[7]);
  unsigned int a4 = pk2f(e[8], e[9]),   a5 = pk2f(e[10], e[11]);
  unsigned int a6 = pk2f(e[12], e[13]), a7 = pk2f(e[14], e[15]);
  unsigned int x0 = __shfl_xor(hh ? a0 : a2, 32);
  unsigned int x1 = __shfl_xor(hh ? a1 : a3, 32);
  unsigned int x2 = __shfl_xor(hh ? a4 : a6, 32);
  unsigned int x3 = __shfl_xor(hh ? a5 : a7, 32);
  uint4 u0 = {hh ? x0 : a0, hh ? x1 : a1, hh ? a2 : x0, hh ? a3 : x1};
  uint4 u1 = {hh ? x2 : a4, hh ? x3 : a5, hh ? a6 : x2, hh ? a7 : x3};
  f0 = __builtin_bit_cast(short8, u0);
  f1 = __builtin_bit_cast(short8, u1);
}

// ---- staging helpers, 4-wave blocks (verified R7-R10) ----
static __device__ __forceinline__ void stage_64x256(const char* gbase, size_t stride,
                                                    char* lds, int wave, int lane) {
#pragma unroll
  for (int i = 0; i < 4; i++) {
    int r = wave * 16 + i * 4 + (lane >> 4);
    int us = (lane & 15) ^ (r & 15);
    load_lds16(gbase + (size_t)r * stride + us * 16, lds + (wave * 16 + i * 4) * 256);
  }
}
static __device__ __forceinline__ void stage_128x256(const char* gbase, size_t stride,
                                                     char* lds, int wave, int lane) {
#pragma unroll
  for (int i = 0; i < 8; i++) {
    int r = wave * 32 + i * 4 + (lane >> 4);
    int us = (lane & 15) ^ (r & 15);
    load_lds16(gbase + (size_t)r * stride + us * 16, lds + (wave * 32 + i * 4) * 256);
  }
}
// 128 bf16 rows x 128 B -> 64 macro-rows x 256 B, macro-swizzled.
static __device__ __forceinline__ void stage_128x128(const char* gbase, size_t stride,
                                                     int colOff, char* lds, int wave,
                                                     int lane) {
#pragma unroll
  for (int i = 0; i < 4; i++) {
    int m = wave * 16 + i * 4 + (lane >> 4);
    int u = (lane & 15) ^ (m & 15);
    int grow = 2 * m + (u >> 3);
    load_lds16(gbase + (size_t)grow * stride + colOff + (u & 7) * 16,
               lds + (wave * 16 + i * 4) * 256);
  }
}
// 64 fp8 key-rows x 128 B -> 32 macro-rows x 256 B (8 KB).
static __device__ __forceinline__ void stage_k8(const char* gbase, char* lds,
                                                int wave, int lane) {
#pragma unroll
  for (int i = 0; i < 2; i++) {
    int m = wave * 8 + i * 4 + (lane >> 4);
    int u = (lane & 15) ^ (m & 15);
    int grow = 2 * m + (u >> 3);
    load_lds16(gbase + (size_t)grow * 128 + (u & 7) * 16,
               lds + (wave * 8 + i * 4) * 256);
  }
}
static __device__ __forceinline__ short8 read_macro(const char* lds, int row, int kunit) {
  int m = row >> 1;
  int u = ((row & 1) << 3) | kunit;
  return *(const short8*)(lds + m * 256 + ((u ^ (m & 15)) * 16));
}

// ---- fused prep: blocks 0..15 convert X; blocks 16..95 convert W/V ----
__global__ __launch_bounds__(256)
void prep_kernel(const float* __restrict__ X, const float* __restrict__ W,
                 const float* __restrict__ V, unsigned short* __restrict__ Xb,
                 unsigned short* __restrict__ XbT, unsigned char* __restrict__ Xf8,
                 unsigned short* __restrict__ Wt, unsigned short* __restrict__ Vt) {
  const int tid = threadIdx.x;
  __shared__ __align__(16) unsigned short Lt[128 * 136];
  if (blockIdx.x < 16) {
    const int n0 = blockIdx.x * 128;
    for (int i = tid; i < 128 * 32; i += 256) {
      int row = i >> 5, c4 = (i & 31) * 4;
      float4v x = *(const float4v*)(X + (size_t)(n0 + row) * D + c4);
      unsigned long long p = pack4(x.x, x.y, x.z, x.w);
      *(unsigned long long*)(Lt + row * 136 + c4) = p;
      *(unsigned long long*)(Xb + (size_t)(n0 + row) * D + c4) = p;
    }
    __syncthreads();
    for (int i = tid; i < 128 * 16; i += 256) {
      int d = i >> 4, g = i & 15;
      short8 v;
#pragma unroll
      for (int j = 0; j < 8; j++) v[j] = (short)Lt[(g * 8 + j) * 136 + d];
      *(short8*)(XbT + (size_t)d * N + n0 + g * 8) = v;
    }
    // Xf8 [n][d-permuted]: chunk c=2t+o holds d[32t+8o..+8) ++ d[32t+16+8o..+8)
    for (int i = tid; i < 128 * 8; i += 256) {
      int row = i >> 3, c = i & 7, t = c >> 1, o8 = (c & 1) * 8;
      const unsigned short* lp = Lt + row * 136;
      int d0 = t * 32 + o8, d1 = t * 32 + 16 + o8;
      short8 xa = *(const short8*)(lp + d0);
      short8 xb = *(const short8*)(lp + d1);
      int w0 = __builtin_amdgcn_cvt_pk_fp8_f32(bf2f(xa[0]), bf2f(xa[1]), 0, false);
      w0 = __builtin_amdgcn_cvt_pk_fp8_f32(bf2f(xa[2]), bf2f(xa[3]), w0, true);
      int w1 = __builtin_amdgcn_cvt_pk_fp8_f32(bf2f(xa[4]), bf2f(xa[5]), 0, false);
      w1 = __builtin_amdgcn_cvt_pk_fp8_f32(bf2f(xa[6]), bf2f(xa[7]), w1, true);
      int w2 = __builtin_amdgcn_cvt_pk_fp8_f32(bf2f(xb[0]), bf2f(xb[1]), 0, false);
      w2 = __builtin_amdgcn_cvt_pk_fp8_f32(bf2f(xb[2]), bf2f(xb[3]), w2, true);
      int w3 = __builtin_amdgcn_cvt_pk_fp8_f32(bf2f(xb[4]), bf2f(xb[5]), 0, false);
      w3 = __builtin_amdgcn_cvt_pk_fp8_f32(bf2f(xb[6]), bf2f(xb[7]), w3, true);
      uint4 st = {(unsigned)w0, (unsigned)w1, (unsigned)w2, (unsigned)w3};
      *(uint4*)(Xf8 + (size_t)(n0 + row) * 128 + c * 16) = st;
    }
  } else {
    const int b = blockIdx.x - 16;
    const int mat = (b >= H) ? 1 : 0;
    const int h = mat ? b - H : b;
    const float* src = (mat ? V : W) + (size_t)h * D * D;
    unsigned short* dst = (mat ? Vt : Wt) + (size_t)h * D * D;
    const float scale = mat ? 1.0f : 0.1275174313f;  // log2(e)/sqrt(128)
    for (int i = tid; i < 128 * 32; i += 256) {
      int d = i >> 5, e4 = (i & 31) * 4;
      float4v w = *(const float4v*)(src + d * D + e4);
      Lt[(e4 + 0) * 136 + d] = f32_to_bf16(w.x * scale);
      Lt[(e4 + 1) * 136 + d] = f32_to_bf16(w.y * scale);
      Lt[(e4 + 2) * 136 + d] = f32_to_bf16(w.z * scale);
      Lt[(e4 + 3) * 136 + d] = f32_to_bf16(w.w * scale);
    }
    __syncthreads();
    for (int i = tid; i < 128 * 16; i += 256) {
      int e = i >> 4, u = i & 15;
      *(uint4*)((char*)dst + (size_t)e * 256 + u * 16) =
          *(const uint4*)((const char*)Lt + (size_t)e * 272 + u * 16);
    }
  }
}

// ---- qprep: one-shot Q fragments (fp8, per-lane opaque 64B blob) ----
// blob layout: [h][qtile16][wave4] x 4096B; frag-pair i at i*1024 + lane*16.
__global__ __launch_bounds__(256)
void qprep_kernel(const unsigned short* __restrict__ Xb,
                  const unsigned short* __restrict__ Wt,
                  unsigned char* __restrict__ Qf8g) {
  __shared__ __align__(16) char smem[32768];
  const int bx = blockIdx.x;
  const int h = bx >> 4;
  const int q0 = (bx & 15) << 7;
  const int tid = threadIdx.x;
  const int wave = tid >> 6, lane = tid & 63;
  const int l = lane & 31, hh = lane >> 5;

  stage_128x256((const char*)(Wt + (size_t)h * D * D), 256, smem, wave, lane);
  short8 xfr[8];
#pragma unroll
  for (int dk = 0; dk < 8; dk++)
    xfr[dk] = *(const short8*)((const char*)Xb +
              (size_t)(q0 + wave * 32 + l) * 256 + dk * 32 + hh * 16);
  __syncthreads();

  float16v qa[4];
#pragma unroll
  for (int et = 0; et < 4; et++) qa[et] = (float16v)0.0f;
#pragma unroll
  for (int et = 0; et < 4; et++) {
    const int r = et * 32 + l;
#pragma unroll
    for (int dk = 0; dk < 8; dk++) {
      short8 wa = *(const short8*)(smem + r * 256 + (((2 * dk + hh) ^ (r & 15)) * 16));
      qa[et] = MFMA32(wa, xfr[dk], qa[et]);
    }
  }
  char* base = (char*)Qf8g + ((size_t)bx * 4 + wave) * 4096;
#pragma unroll
  for (int et = 0; et < 4; et++) {
    long long f0, f1;
    regs_to_f8frags(qa[et], hh, f0, f1);
    uint4 st = {(unsigned)(unsigned long long)f0,
                (unsigned)((unsigned long long)f0 >> 32),
                (unsigned)(unsigned long long)f1,
                (unsigned)((unsigned long long)f1 >> 32)};
    *(uint4*)(base + et * 1024 + lane * 16) = st;
  }
}

// ---- attention: 4-wave blocks, split-k x2, fp8 S, batched-ksub ILP ----
__global__ __launch_bounds__(256)
void attn_kernel(const unsigned char* __restrict__ Qf8g,
                 const unsigned char* __restrict__ Xf8,
                 const unsigned short* __restrict__ XbT,
                 const unsigned short* __restrict__ Vt,
                 unsigned short* __restrict__ Opart, float* __restrict__ Lsum) {
  __shared__ __align__(16) char smem[49152];
  char* XA = smem;            // 16K: XbT dbuf A / Vt half0 / out staging
  char* XB = smem + 16384;    // 16K: XbT dbuf B / Vt half1 / out staging
  char* KA = smem + 32768;    // 8K: fp8 K dbuf A
  char* KB = smem + 40960;    // 8K: fp8 K dbuf B
  const int bx = blockIdx.x;
  const int kh = bx & 1;
  const int qt = (bx >> 1) & 15;
  const int q0 = qt << 7;
  const int h = bx >> 5;
  const int tid = threadIdx.x;
  const int wave = tid >> 6, lane = tid & 63;
  const int l = lane & 31, hh = lane >> 5;

  const char* Xf8B = (const char*)Xf8;
  const char* XbTB = (const char*)XbT;
  const char* VtB = (const char*)(Vt + (size_t)h * D * D);
  const int kbase = kh * (N / 2);

  // 1. stage tile0 (K + XsT), load precomputed Q fragments from L2
  stage_k8(Xf8B + (size_t)kbase * 128, KA, wave, lane);
  stage_128x128(XbTB, 4096, kbase * 2, XA, wave, lane);
  long long qf8[8];
  {
    const char* qp = (const char*)Qf8g + (((size_t)h * 16 + qt) * 4 + wave) * 4096;
#pragma unroll
    for (int i = 0; i < 4; i++) {
      uint4 v = *(const uint4*)(qp + i * 1024 + lane * 16);
      qf8[2 * i] = mk64(v.x, v.y);
      qf8[2 * i + 1] = mk64(v.z, v.w);
    }
  }
  float16v Tacc[4];
#pragma unroll
  for (int dt = 0; dt < 4; dt++) Tacc[dt] = (float16v)0.0f;
  float lsum = 0.0f;
  __syncthreads();

  // 2. main loop: dbuf prefetch, batched ksubs (2 indep S chains -> exp -> T)
  for (int kt = 0; kt < NT; kt++) {
    const char* curK = (kt & 1) ? KB : KA;
    const char* curX = (kt & 1) ? XB : XA;
    char* altK = (kt & 1) ? KA : KB;
    char* altX = (kt & 1) ? XA : XB;
    if (kt + 1 < NT) {
      const int k0n = kbase + (kt + 1) * 64;
      stage_k8(Xf8B + (size_t)k0n * 128, altK, wave, lane);
      stage_128x128(XbTB, 4096, k0n * 2, altX, wave, lane);
    } else {
      stage_64x256(VtB, 256, altX, wave, lane);  // Vt rows 0..63 -> XA (NT even)
    }
    // S-phase: both 32-key subtiles as independent chains
    float16v s0 = (float16v)0.0f, s1 = (float16v)0.0f;
    {
      const int m0 = l >> 1, r0 = (l & 1) << 3;          // krow0 = l
      const int m1 = (32 + l) >> 1, r1 = (l & 1) << 3;   // krow1 = 32+l
#pragma unroll
      for (int t = 0; t < 4; t++) {
        int u0 = (r0 | (t * 2 + hh)) ^ (m0 & 15);
        int u1 = (r1 | (t * 2 + hh)) ^ (m1 & 15);
        uint4 w0 = *(const uint4*)(curK + m0 * 256 + u0 * 16);
        uint4 w1 = *(const uint4*)(curK + m1 * 256 + u1 * 16);
        s0 = MFMA8(mk64(w0.x, w0.y), qf8[2 * t], s0);
        s1 = MFMA8(mk64(w1.x, w1.y), qf8[2 * t], s1);
        s0 = MFMA8(mk64(w0.z, w0.w), qf8[2 * t + 1], s0);
        s1 = MFMA8(mk64(w1.z, w1.w), qf8[2 * t + 1], s1);
      }
    }
    short8 pf0[2], pf1[2];
    regs_to_pfrags(s0, hh, lsum, pf0[0], pf0[1]);
    regs_to_pfrags(s1, hh, lsum, pf1[0], pf1[1]);
    // T-phase: 16 MFMAs, 4 independent chains (dt)
#pragma unroll
    for (int kk = 0; kk < 2; kk++)
#pragma unroll
      for (int dt = 0; dt < 4; dt++) {
        short8 xt0 = read_macro(curX, dt * 32 + l, kk * 2 + hh);
        Tacc[dt] = MFMA32(xt0, pf0[kk], Tacc[dt]);
        short8 xt1 = read_macro(curX, dt * 32 + l, 4 + kk * 2 + hh);
        Tacc[dt] = MFMA32(xt1, pf1[kk], Tacc[dt]);
      }
    __syncthreads();
  }

  float tot = lsum + __shfl_xor(lsum, 32);
  if (hh == 0) Lsum[(size_t)(h * 2 + kh) * N + q0 + wave * 32 + l] = tot;

  // 3. epilogue: O^T[e][q] = V^T[e][d] @ T^T[d][q]; Vt half1 prefetch
  stage_64x256(VtB + 64 * 256, 256, XB, wave, lane);  // rows 64..127 -> XB
  short8 tb[8];
#pragma unroll
  for (int dt = 0; dt < 4; dt++)
    regs_to_bfrags(Tacc[dt], hh, tb[2 * dt], tb[2 * dt + 1]);

  float16v oacc[4];
#pragma unroll
  for (int et = 0; et < 4; et++) oacc[et] = (float16v)0.0f;
#pragma unroll
  for (int et = 0; et < 2; et++) {  // Vt half0 (XA, staged during kt=15)
    const int r = et * 32 + l;
#pragma unroll
    for (int dk = 0; dk < 8; dk++) {
      short8 va = *(const short8*)(XA + r * 256 + (((2 * dk + hh) ^ (r & 15)) * 16));
      oacc[et] = MFMA32(va, tb[dk], oacc[et]);
    }
  }
  __syncthreads();  // Vt half1 ready
#pragma unroll
  for (int et = 2; et < 4; et++) {
    const int r = (et - 2) * 32 + l;
#pragma unroll
    for (int dk = 0; dk < 8; dk++) {
      short8 va = *(const short8*)(XB + r * 256 + (((2 * dk + hh) ^ (r & 15)) * 16));
      oacc[et] = MFMA32(va, tb[dk], oacc[et]);
    }
  }

  // 4. transpose via [0,32K) + coalesced fp16 partial store
  unsigned short* Oph = Opart + (size_t)(h * 2 + kh) * N * D;
#pragma unroll
  for (int pass = 0; pass < 2; pass++) {
    __syncthreads();
    const int qrow = wave * 32 + l;
#pragma unroll
    for (int etL = 0; etL < 2; etL++) {
      int et = pass * 2 + etL;
#pragma unroll
      for (int g = 0; g < 4; g++) {
        int unit = etL * 8 + 2 * g + hh;
        float4v v;
        v.x = oacc[et][4 * g + 0];
        v.y = oacc[et][4 * g + 1];
        v.z = oacc[et][4 * g + 2];
        v.w = oacc[et][4 * g + 3];
        *(float4v*)(smem + qrow * 256 + ((unit ^ (qrow & 15)) * 16)) = v;
      }
    }
    __syncthreads();
#pragma unroll
    for (int i = 0; i < 8; i++) {
      int idx = i * 256 + tid;
      int qr = idx >> 4, up = idx & 15, u = up ^ (qr & 15);
      float4v v = *(const float4v*)(smem + qr * 256 + up * 16);
      auto h0 = __builtin_amdgcn_cvt_pkrtz(v.x, v.y);
      auto h1 = __builtin_amdgcn_cvt_pkrtz(v.z, v.w);
      uint2 st = {__builtin_bit_cast(unsigned int, h0),
                  __builtin_bit_cast(unsigned int, h1)};
      *(uint2*)(Oph + (size_t)(q0 + qr) * D + pass * 64 + u * 4) = st;
    }
  }
}

// ---- reduce: out[n][e] = sum_h (O[h,0]+O[h,1]) / (l[h,0]+l[h,1]) ----
__global__ __launch_bounds__(256)
void reduce_kernel(const unsigned short* __restrict__ Opart,
                   const float* __restrict__ Lsum, float* __restrict__ out) {
  int idx = blockIdx.x * 256 + threadIdx.x;  // float4 unit, 65536 total
  int n = idx >> 5;
  const uint2* base = (const uint2*)Opart;
  float4v acc = (float4v)0.0f;
#pragma unroll 8
  for (int h = 0; h < H; h++) {
    float lt = Lsum[(size_t)(2 * h) * N + n] + Lsum[(size_t)(2 * h + 1) * N + n];
    float il = __builtin_amdgcn_rcpf(lt);
    uint2 a = base[(size_t)(2 * h) * (N * D / 4) + idx];
    uint2 b = base[(size_t)(2 * h + 1) * (N * D / 4) + idx];
    float4v fa = __builtin_convertvector(__builtin_bit_cast(half4v, a), float4v);
    float4v fb = __builtin_convertvector(__builtin_bit_cast(half4v, b), float4v);
    acc += (fa + fb) * il;
  }
  *(float4v*)(out + (size_t)idx * 4) = acc;
}

extern "C" void kernel_launch(void* const* d_in, const int* in_sizes, int n_in,
                              void* d_out, int out_size, void* d_ws, size_t ws_size,
                              hipStream_t stream) {
  const float* X = (const float*)d_in[0];
  const float* W = (const float*)d_in[1];
  const float* V = (const float*)d_in[2];
  float* out = (float*)d_out;

  unsigned short* Xb = (unsigned short*)d_ws;        // N*D bf16
  unsigned short* XbT = Xb + (size_t)N * D;          // D*N bf16
  unsigned short* Wt = XbT + (size_t)N * D;          // H*D*D bf16 (log2e-scaled)
  unsigned short* Vt = Wt + (size_t)H * D * D;       // H*D*D bf16
  unsigned char* Xf8 = (unsigned char*)(Vt + (size_t)H * D * D);   // N*D fp8 (perm)
  unsigned char* Qf8g = Xf8 + (size_t)N * D;                       // H*16*4*4096 B
  unsigned short* Opart = (unsigned short*)(Qf8g + (size_t)H * 16 * 4 * 4096);
  float* Lsum = (float*)(Opart + (size_t)H * 2 * N * D);           // H*2*N fp32

  prep_kernel<<<dim3(16 + 2 * H), 256, 0, stream>>>(X, W, V, Xb, XbT, Xf8, Wt, Vt);
  qprep_kernel<<<dim3(16 * H), 256, 0, stream>>>(Xb, Wt, Qf8g);
  attn_kernel<<<dim3(NT * 2 * H), 256, 0, stream>>>(Qf8g, Xf8, XbT, Vt, Opart, Lsum);
  reduce_kernel<<<dim3(N * D / 4 / 256), 256, 0, stream>>>(Opart, Lsum, out);
}

// Round 13
// 195.571 us; speedup vs baseline: 1.0240x; 1.0032x over previous
//
#include <hip/hip_runtime.h>
#include <hip/hip_bf16.h>
#include <stdint.h>

#define N 2048
#define D 128
#define H 40
#define NT 16  // 64-key tiles per k-half

typedef __attribute__((ext_vector_type(8))) short short8;
typedef __attribute__((ext_vector_type(4))) float float4v;
typedef __attribute__((ext_vector_type(16))) float float16v;
typedef __attribute__((ext_vector_type(4))) _Float16 half4v;

static __device__ __forceinline__ unsigned short f32_to_bf16(float f) {
  unsigned int u = __builtin_bit_cast(unsigned int, f);
  unsigned int rounding = 0x7FFFu + ((u >> 16) & 1u);
  return (unsigned short)((u + rounding) >> 16);
}

static __device__ __forceinline__ unsigned int pk2(float lo, float hi) {
  return (unsigned int)f32_to_bf16(lo) | ((unsigned int)f32_to_bf16(hi) << 16);
}

// Fast pack: round-half-up + v_perm_b32 byte gather (3 VALU). Hot path only.
static __device__ __forceinline__ unsigned int pk2f(float lo, float hi) {
  unsigned int a = __builtin_bit_cast(unsigned int, lo) + 0x8000u;
  unsigned int b = __builtin_bit_cast(unsigned int, hi) + 0x8000u;
  return __builtin_amdgcn_perm(b, a, 0x07060302u);
}

static __device__ __forceinline__ unsigned long long pack4(float x0, float x1,
                                                           float x2, float x3) {
  return (unsigned long long)pk2(x0, x1) | ((unsigned long long)pk2(x2, x3) << 32);
}

static __device__ __forceinline__ float fast_exp2(float x) {
#if __has_builtin(__builtin_amdgcn_exp2f)
  return __builtin_amdgcn_exp2f(x);
#else
  return __expf(0.69314718056f * x);
#endif
}

static __device__ __forceinline__ float bf2f(unsigned short u) {
  unsigned int x = ((unsigned int)u) << 16;
  return __builtin_bit_cast(float, x);
}

static __device__ __forceinline__ long long mk64(unsigned int lo, unsigned int hi) {
  return (long long)(((unsigned long long)hi << 32) | lo);
}

static __device__ __forceinline__ void load_lds16(const void* g, void* l) {
  __builtin_amdgcn_global_load_lds(
      (const __attribute__((address_space(1))) unsigned int*)g,
      (__attribute__((address_space(3))) unsigned int*)l, 16, 0, 0);
}

#define MFMA32(a, b, c) __builtin_amdgcn_mfma_f32_32x32x16_bf16((a), (b), (c), 0, 0, 0)
#define MFMA8(a, b, c) __builtin_amdgcn_mfma_f32_32x32x16_fp8_fp8((a), (b), (c), 0, 0, 0)

// 32x32 C-layout regs -> two bf16 B-fragments (verified R3-R12).
static __device__ __forceinline__ void regs_to_bfrags(const float16v c, int hh,
                                                      short8& f0, short8& f1) {
  unsigned int a0 = pk2f(c[0], c[1]),   a1 = pk2f(c[2], c[3]);
  unsigned int a2 = pk2f(c[4], c[5]),   a3 = pk2f(c[6], c[7]);
  unsigned int a4 = pk2f(c[8], c[9]),   a5 = pk2f(c[10], c[11]);
  unsigned int a6 = pk2f(c[12], c[13]), a7 = pk2f(c[14], c[15]);
  unsigned int x0 = __shfl_xor(hh ? a0 : a2, 32);
  unsigned int x1 = __shfl_xor(hh ? a1 : a3, 32);
  unsigned int x2 = __shfl_xor(hh ? a4 : a6, 32);
  unsigned int x3 = __shfl_xor(hh ? a5 : a7, 32);
  uint4 u0 = {hh ? x0 : a0, hh ? x1 : a1, hh ? a2 : x0, hh ? a3 : x1};
  uint4 u1 = {hh ? x2 : a4, hh ? x3 : a5, hh ? a6 : x2, hh ? a7 : x3};
  f0 = __builtin_bit_cast(short8, u0);
  f1 = __builtin_bit_cast(short8, u1);
}

// Byte-granularity version for fp8 e4m3 B-frags (Q scaled by 64). (Verified R10-R12.)
static __device__ __forceinline__ void regs_to_f8frags(const float16v c, int hh,
                                                       long long& f0, long long& f1) {
  const float s = 64.0f;
  int v0 = __builtin_amdgcn_cvt_pk_fp8_f32(c[0] * s, c[1] * s, 0, false);
  v0 = __builtin_amdgcn_cvt_pk_fp8_f32(c[2] * s, c[3] * s, v0, true);
  int v1 = __builtin_amdgcn_cvt_pk_fp8_f32(c[4] * s, c[5] * s, 0, false);
  v1 = __builtin_amdgcn_cvt_pk_fp8_f32(c[6] * s, c[7] * s, v1, true);
  int v2 = __builtin_amdgcn_cvt_pk_fp8_f32(c[8] * s, c[9] * s, 0, false);
  v2 = __builtin_amdgcn_cvt_pk_fp8_f32(c[10] * s, c[11] * s, v2, true);
  int v3 = __builtin_amdgcn_cvt_pk_fp8_f32(c[12] * s, c[13] * s, 0, false);
  v3 = __builtin_amdgcn_cvt_pk_fp8_f32(c[14] * s, c[15] * s, v3, true);
  int t0 = __shfl_xor(hh ? v0 : v1, 32);
  int t1 = __shfl_xor(hh ? v2 : v3, 32);
  f0 = hh ? mk64((unsigned)t0, (unsigned)v1) : mk64((unsigned)v0, (unsigned)t0);
  f1 = hh ? mk64((unsigned)t1, (unsigned)v3) : mk64((unsigned)v2, (unsigned)t1);
}

// exp2(s/64), row-sum, pack bf16 P-fragments. (Verified R10-R12.)
static __device__ __forceinline__ void regs_to_pfrags(const float16v s, int hh,
                                                      float& lsum, short8& f0,
                                                      short8& f1) {
  float e[16];
  float acc = 0.0f;
#pragma unroll
  for (int i = 0; i < 16; i++) { e[i] = fast_exp2(s[i] * 0.015625f); acc += e[i]; }
  lsum += acc;
  unsigned int a0 = pk2f(e[0], e[1]),   a1 = pk2f(e[2], e[3]);
  unsigned int a2 = pk2f(e[4], e[5]),   a3 = pk2f(e[6], e[7]);
  unsigned int a4 = pk2f(e[8], e[9]),   a5 = pk2f(e[10], e[11]);
  unsigned int a6 = pk2f(e[12], e[13]), a7 = pk2f(e[14], e[15]);
  unsigned int x0 = __shfl_xor(hh ? a0 : a2, 32);
  unsigned int x1 = __shfl_xor(hh ? a1 : a3, 32);
  unsigned int x2 = __shfl_xor(hh ? a4 : a6, 32);
  unsigned int x3 = __shfl_xor(hh ? a5 : a7, 32);
  uint4 u0 = {hh ? x0 : a0, hh ? x1 : a1, hh ? a2 : x0, hh ? a3 : x1};
  uint4 u1 = {hh ? x2 : a4, hh ? x3 : a5, hh ? a6 : x2, hh ? a7 : x3};
  f0 = __builtin_bit_cast(short8, u0);
  f1 = __builtin_bit_cast(short8, u1);
}

// ---- staging helpers, 4-wave blocks (verified R7-R12) ----
static __device__ __forceinline__ void stage_64x256(const char* gbase, size_t stride,
                                                    char* lds, int wave, int lane) {
#pragma unroll
  for (int i = 0; i < 4; i++) {
    int r = wave * 16 + i * 4 + (lane >> 4);
    int us = (lane & 15) ^ (r & 15);
    load_lds16(gbase + (size_t)r * stride + us * 16, lds + (wave * 16 + i * 4) * 256);
  }
}
static __device__ __forceinline__ void stage_128x256(const char* gbase, size_t stride,
                                                     char* lds, int wave, int lane) {
#pragma unroll
  for (int i = 0; i < 8; i++) {
    int r = wave * 32 + i * 4 + (lane >> 4);
    int us = (lane & 15) ^ (r & 15);
    load_lds16(gbase + (size_t)r * stride + us * 16, lds + (wave * 32 + i * 4) * 256);
  }
}
// 128 bf16 rows x 128 B -> 64 macro-rows x 256 B, macro-swizzled.
static __device__ __forceinline__ void stage_128x128(const char* gbase, size_t stride,
                                                     int colOff, char* lds, int wave,
                                                     int lane) {
#pragma unroll
  for (int i = 0; i < 4; i++) {
    int m = wave * 16 + i * 4 + (lane >> 4);
    int u = (lane & 15) ^ (m & 15);
    int grow = 2 * m + (u >> 3);
    load_lds16(gbase + (size_t)grow * stride + colOff + (u & 7) * 16,
               lds + (wave * 16 + i * 4) * 256);
  }
}
// 64 fp8 key-rows x 128 B -> 32 macro-rows x 256 B (8 KB).
static __device__ __forceinline__ void stage_k8(const char* gbase, char* lds,
                                                int wave, int lane) {
#pragma unroll
  for (int i = 0; i < 2; i++) {
    int m = wave * 8 + i * 4 + (lane >> 4);
    int u = (lane & 15) ^ (m & 15);
    int grow = 2 * m + (u >> 3);
    load_lds16(gbase + (size_t)grow * 128 + (u & 7) * 16,
               lds + (wave * 8 + i * 4) * 256);
  }
}
static __device__ __forceinline__ short8 read_macro(const char* lds, int row, int kunit) {
  int m = row >> 1;
  int u = ((row & 1) << 3) | kunit;
  return *(const short8*)(lds + m * 256 + ((u ^ (m & 15)) * 16));
}

// ---- fused prep: blocks 0..15 convert X; blocks 16..95 convert W/V ----
__global__ __launch_bounds__(256)
void prep_kernel(const float* __restrict__ X, const float* __restrict__ W,
                 const float* __restrict__ V, unsigned short* __restrict__ Xb,
                 unsigned short* __restrict__ XbT, unsigned char* __restrict__ Xf8,
                 unsigned short* __restrict__ Wt, unsigned short* __restrict__ Vt) {
  const int tid = threadIdx.x;
  __shared__ __align__(16) unsigned short Lt[128 * 136];
  if (blockIdx.x < 16) {
    const int n0 = blockIdx.x * 128;
    for (int i = tid; i < 128 * 32; i += 256) {
      int row = i >> 5, c4 = (i & 31) * 4;
      float4v x = *(const float4v*)(X + (size_t)(n0 + row) * D + c4);
      unsigned long long p = pack4(x.x, x.y, x.z, x.w);
      *(unsigned long long*)(Lt + row * 136 + c4) = p;
      *(unsigned long long*)(Xb + (size_t)(n0 + row) * D + c4) = p;
    }
    __syncthreads();
    for (int i = tid; i < 128 * 16; i += 256) {
      int d = i >> 4, g = i & 15;
      short8 v;
#pragma unroll
      for (int j = 0; j < 8; j++) v[j] = (short)Lt[(g * 8 + j) * 136 + d];
      *(short8*)(XbT + (size_t)d * N + n0 + g * 8) = v;
    }
    // Xf8 [n][d-permuted]: chunk c=2t+o holds d[32t+8o..+8) ++ d[32t+16+8o..+8)
    for (int i = tid; i < 128 * 8; i += 256) {
      int row = i >> 3, c = i & 7, t = c >> 1, o8 = (c & 1) * 8;
      const unsigned short* lp = Lt + row * 136;
      int d0 = t * 32 + o8, d1 = t * 32 + 16 + o8;
      short8 xa = *(const short8*)(lp + d0);
      short8 xb = *(const short8*)(lp + d1);
      int w0 = __builtin_amdgcn_cvt_pk_fp8_f32(bf2f(xa[0]), bf2f(xa[1]), 0, false);
      w0 = __builtin_amdgcn_cvt_pk_fp8_f32(bf2f(xa[2]), bf2f(xa[3]), w0, true);
      int w1 = __builtin_amdgcn_cvt_pk_fp8_f32(bf2f(xa[4]), bf2f(xa[5]), 0, false);
      w1 = __builtin_amdgcn_cvt_pk_fp8_f32(bf2f(xa[6]), bf2f(xa[7]), w1, true);
      int w2 = __builtin_amdgcn_cvt_pk_fp8_f32(bf2f(xb[0]), bf2f(xb[1]), 0, false);
      w2 = __builtin_amdgcn_cvt_pk_fp8_f32(bf2f(xb[2]), bf2f(xb[3]), w2, true);
      int w3 = __builtin_amdgcn_cvt_pk_fp8_f32(bf2f(xb[4]), bf2f(xb[5]), 0, false);
      w3 = __builtin_amdgcn_cvt_pk_fp8_f32(bf2f(xb[6]), bf2f(xb[7]), w3, true);
      uint4 st = {(unsigned)w0, (unsigned)w1, (unsigned)w2, (unsigned)w3};
      *(uint4*)(Xf8 + (size_t)(n0 + row) * 128 + c * 16) = st;
    }
  } else {
    const int b = blockIdx.x - 16;
    const int mat = (b >= H) ? 1 : 0;
    const int h = mat ? b - H : b;
    const float* src = (mat ? V : W) + (size_t)h * D * D;
    unsigned short* dst = (mat ? Vt : Wt) + (size_t)h * D * D;
    const float scale = mat ? 1.0f : 0.1275174313f;  // log2(e)/sqrt(128)
    for (int i = tid; i < 128 * 32; i += 256) {
      int d = i >> 5, e4 = (i & 31) * 4;
      float4v w = *(const float4v*)(src + d * D + e4);
      Lt[(e4 + 0) * 136 + d] = f32_to_bf16(w.x * scale);
      Lt[(e4 + 1) * 136 + d] = f32_to_bf16(w.y * scale);
      Lt[(e4 + 2) * 136 + d] = f32_to_bf16(w.z * scale);
      Lt[(e4 + 3) * 136 + d] = f32_to_bf16(w.w * scale);
    }
    __syncthreads();
    for (int i = tid; i < 128 * 16; i += 256) {
      int e = i >> 4, u = i & 15;
      *(uint4*)((char*)dst + (size_t)e * 256 + u * 16) =
          *(const uint4*)((const char*)Lt + (size_t)e * 272 + u * 16);
    }
  }
}

// ---- qprep: one-shot Q fragments (fp8, per-lane opaque 64B blob) ----
// blob layout: [h][qtile16][wave4] x 4096B; frag-pair i at i*1024 + lane*16.
__global__ __launch_bounds__(256)
void qprep_kernel(const unsigned short* __restrict__ Xb,
                  const unsigned short* __restrict__ Wt,
                  unsigned char* __restrict__ Qf8g) {
  __shared__ __align__(16) char smem[32768];
  const int bx = blockIdx.x;
  const int h = bx >> 4;
  const int q0 = (bx & 15) << 7;
  const int tid = threadIdx.x;
  const int wave = tid >> 6, lane = tid & 63;
  const int l = lane & 31, hh = lane >> 5;

  stage_128x256((const char*)(Wt + (size_t)h * D * D), 256, smem, wave, lane);
  short8 xfr[8];
#pragma unroll
  for (int dk = 0; dk < 8; dk++)
    xfr[dk] = *(const short8*)((const char*)Xb +
              (size_t)(q0 + wave * 32 + l) * 256 + dk * 32 + hh * 16);
  __syncthreads();

  float16v qa[4];
#pragma unroll
  for (int et = 0; et < 4; et++) qa[et] = (float16v)0.0f;
#pragma unroll
  for (int et = 0; et < 4; et++) {
    const int r = et * 32 + l;
#pragma unroll
    for (int dk = 0; dk < 8; dk++) {
      short8 wa = *(const short8*)(smem + r * 256 + (((2 * dk + hh) ^ (r & 15)) * 16));
      qa[et] = MFMA32(wa, xfr[dk], qa[et]);
    }
  }
  char* base = (char*)Qf8g + ((size_t)bx * 4 + wave) * 4096;
#pragma unroll
  for (int et = 0; et < 4; et++) {
    long long f0, f1;
    regs_to_f8frags(qa[et], hh, f0, f1);
    uint4 st = {(unsigned)(unsigned long long)f0,
                (unsigned)((unsigned long long)f0 >> 32),
                (unsigned)(unsigned long long)f1,
                (unsigned)((unsigned long long)f1 >> 32)};
    *(uint4*)(base + et * 1024 + lane * 16) = st;
  }
}

// ---- attention: 32 KB arena (single XbT buf + K dbuf), 2 barriers/tile ----
__global__ __launch_bounds__(256)
void attn_kernel(const unsigned char* __restrict__ Qf8g,
                 const unsigned char* __restrict__ Xf8,
                 const unsigned short* __restrict__ XbT,
                 const unsigned short* __restrict__ Vt,
                 unsigned short* __restrict__ Opart, float* __restrict__ Lsum) {
  __shared__ __align__(16) char smem[32768];
  char* Xbuf = smem;           // 16K: XbT tile (single) / Vt half1 / out staging
  char* KA = smem + 16384;     // 8K: fp8 K dbuf A   (KA+KB = Vt half0 region)
  char* KB = smem + 24576;     // 8K: fp8 K dbuf B
  const int bx = blockIdx.x;
  const int kh = bx & 1;
  const int qt = (bx >> 1) & 15;
  const int q0 = qt << 7;
  const int h = bx >> 5;
  const int tid = threadIdx.x;
  const int wave = tid >> 6, lane = tid & 63;
  const int l = lane & 31, hh = lane >> 5;

  const char* Xf8B = (const char*)Xf8;
  const char* XbTB = (const char*)XbT;
  const char* VtB = (const char*)(Vt + (size_t)h * D * D);
  const int kbase = kh * (N / 2);

  // 1. stage K(0); load precomputed Q fragments from L2
  stage_k8(Xf8B + (size_t)kbase * 128, KA, wave, lane);
  long long qf8[8];
  {
    const char* qp = (const char*)Qf8g + (((size_t)h * 16 + qt) * 4 + wave) * 4096;
#pragma unroll
    for (int i = 0; i < 4; i++) {
      uint4 v = *(const uint4*)(qp + i * 1024 + lane * 16);
      qf8[2 * i] = mk64(v.x, v.y);
      qf8[2 * i + 1] = mk64(v.z, v.w);
    }
  }
  float16v Tacc[4];
#pragma unroll
  for (int dt = 0; dt < 4; dt++) Tacc[dt] = (float16v)0.0f;
  float lsum = 0.0f;
  __syncthreads();  // K(0) ready

  // 2. main loop: stage XbT(kt)+K(kt+1) during S-phase; 2 barriers/tile
  for (int kt = 0; kt < NT; kt++) {
    const char* curK = (kt & 1) ? KB : KA;
    char* altK = (kt & 1) ? KA : KB;
    const int k0 = kbase + kt * 64;
    stage_128x128(XbTB, 4096, k0 * 2, Xbuf, wave, lane);
    if (kt + 1 < NT)
      stage_k8(Xf8B + (size_t)(k0 + 64) * 128, altK, wave, lane);
    // S-phase from curK: both 32-key subtiles as independent chains
    float16v s0 = (float16v)0.0f, s1 = (float16v)0.0f;
    {
      const int m0 = l >> 1, r0 = (l & 1) << 3;          // krow0 = l
      const int m1 = (32 + l) >> 1;                      // krow1 = 32+l
#pragma unroll
      for (int t = 0; t < 4; t++) {
        int u0 = (r0 | (t * 2 + hh)) ^ (m0 & 15);
        int u1 = (r0 | (t * 2 + hh)) ^ (m1 & 15);
        uint4 w0 = *(const uint4*)(curK + m0 * 256 + u0 * 16);
        uint4 w1 = *(const uint4*)(curK + m1 * 256 + u1 * 16);
        s0 = MFMA8(mk64(w0.x, w0.y), qf8[2 * t], s0);
        s1 = MFMA8(mk64(w1.x, w1.y), qf8[2 * t], s1);
        s0 = MFMA8(mk64(w0.z, w0.w), qf8[2 * t + 1], s0);
        s1 = MFMA8(mk64(w1.z, w1.w), qf8[2 * t + 1], s1);
      }
    }
    short8 pf0[2], pf1[2];
    regs_to_pfrags(s0, hh, lsum, pf0[0], pf0[1]);
    regs_to_pfrags(s1, hh, lsum, pf1[0], pf1[1]);
    __syncthreads();  // XbT(kt) + K(kt+1) DMA drained; Xbuf ready
    // T-phase from Xbuf: 16 MFMAs, 4 independent chains
#pragma unroll
    for (int kk = 0; kk < 2; kk++)
#pragma unroll
      for (int dt = 0; dt < 4; dt++) {
        short8 xt0 = read_macro(Xbuf, dt * 32 + l, kk * 2 + hh);
        Tacc[dt] = MFMA32(xt0, pf0[kk], Tacc[dt]);
        short8 xt1 = read_macro(Xbuf, dt * 32 + l, 4 + kk * 2 + hh);
        Tacc[dt] = MFMA32(xt1, pf1[kk], Tacc[dt]);
      }
    __syncthreads();  // all waves done with Xbuf before next stage
  }

  float tot = lsum + __shfl_xor(lsum, 32);
  if (hh == 0) Lsum[(size_t)(h * 2 + kh) * N + q0 + wave * 32 + l] = tot;

  // 3. epilogue: stage Vt (half0 -> K region 16K, half1 -> Xbuf 16K)
  stage_64x256(VtB, 256, KA, wave, lane);
  stage_64x256(VtB + 64 * 256, 256, Xbuf, wave, lane);
  short8 tb[8];
#pragma unroll
  for (int dt = 0; dt < 4; dt++)
    regs_to_bfrags(Tacc[dt], hh, tb[2 * dt], tb[2 * dt + 1]);
  __syncthreads();  // Vt ready

  float16v oacc[4];
#pragma unroll
  for (int et = 0; et < 4; et++) oacc[et] = (float16v)0.0f;
#pragma unroll
  for (int et = 0; et < 2; et++) {  // Vt rows 0..63 in K region
    const int r = et * 32 + l;
#pragma unroll
    for (int dk = 0; dk < 8; dk++) {
      short8 va = *(const short8*)(KA + r * 256 + (((2 * dk + hh) ^ (r & 15)) * 16));
      oacc[et] = MFMA32(va, tb[dk], oacc[et]);
    }
  }
#pragma unroll
  for (int et = 2; et < 4; et++) {  // Vt rows 64..127 in Xbuf (local rows 0..63)
    const int r = (et - 2) * 32 + l;
#pragma unroll
    for (int dk = 0; dk < 8; dk++) {
      short8 va = *(const short8*)(Xbuf + r * 256 + (((2 * dk + hh) ^ (r & 15)) * 16));
      oacc[et] = MFMA32(va, tb[dk], oacc[et]);
    }
  }

  // 4. transpose via full 32K arena + coalesced fp16 partial store
  unsigned short* Oph = Opart + (size_t)(h * 2 + kh) * N * D;
#pragma unroll
  for (int pass = 0; pass < 2; pass++) {
    __syncthreads();
    const int qrow = wave * 32 + l;
#pragma unroll
    for (int etL = 0; etL < 2; etL++) {
      int et = pass * 2 + etL;
#pragma unroll
      for (int g = 0; g < 4; g++) {
        int unit = etL * 8 + 2 * g + hh;
        float4v v;
        v.x = oacc[et][4 * g + 0];
        v.y = oacc[et][4 * g + 1];
        v.z = oacc[et][4 * g + 2];
        v.w = oacc[et][4 * g + 3];
        *(float4v*)(smem + qrow * 256 + ((unit ^ (qrow & 15)) * 16)) = v;
      }
    }
    __syncthreads();
#pragma unroll
    for (int i = 0; i < 8; i++) {
      int idx = i * 256 + tid;
      int qr = idx >> 4, up = idx & 15, u = up ^ (qr & 15);
      float4v v = *(const float4v*)(smem + qr * 256 + up * 16);
      auto h0 = __builtin_amdgcn_cvt_pkrtz(v.x, v.y);
      auto h1 = __builtin_amdgcn_cvt_pkrtz(v.z, v.w);
      uint2 st = {__builtin_bit_cast(unsigned int, h0),
                  __builtin_bit_cast(unsigned int, h1)};
      *(uint2*)(Oph + (size_t)(q0 + qr) * D + pass * 64 + u * 4) = st;
    }
  }
}

// ---- reduce: out[n][e] = sum_h (O[h,0]+O[h,1]) / (l[h,0]+l[h,1]) ----
__global__ __launch_bounds__(256)
void reduce_kernel(const unsigned short* __restrict__ Opart,
                   const float* __restrict__ Lsum, float* __restrict__ out) {
  int idx = blockIdx.x * 256 + threadIdx.x;  // float4 unit, 65536 total
  int n = idx >> 5;
  const uint2* base = (const uint2*)Opart;
  float4v acc = (float4v)0.0f;
#pragma unroll 8
  for (int h = 0; h < H; h++) {
    float lt = Lsum[(size_t)(2 * h) * N + n] + Lsum[(size_t)(2 * h + 1) * N + n];
    float il = __builtin_amdgcn_rcpf(lt);
    uint2 a = base[(size_t)(2 * h) * (N * D / 4) + idx];
    uint2 b = base[(size_t)(2 * h + 1) * (N * D / 4) + idx];
    float4v fa = __builtin_convertvector(__builtin_bit_cast(half4v, a), float4v);
    float4v fb = __builtin_convertvector(__builtin_bit_cast(half4v, b), float4v);
    acc += (fa + fb) * il;
  }
  *(float4v*)(out + (size_t)idx * 4) = acc;
}

extern "C" void kernel_launch(void* const* d_in, const int* in_sizes, int n_in,
                              void* d_out, int out_size, void* d_ws, size_t ws_size,
                              hipStream_t stream) {
  const float* X = (const float*)d_in[0];
  const float* W = (const float*)d_in[1];
  const float* V = (const float*)d_in[2];
  float* out = (float*)d_out;

  unsigned short* Xb = (unsigned short*)d_ws;        // N*D bf16
  unsigned short* XbT = Xb + (size_t)N * D;          // D*N bf16
  unsigned short* Wt = XbT + (size_t)N * D;          // H*D*D bf16 (log2e-scaled)
  unsigned short* Vt = Wt + (size_t)H * D * D;       // H*D*D bf16
  unsigned char* Xf8 = (unsigned char*)(Vt + (size_t)H * D * D);   // N*D fp8 (perm)
  unsigned char* Qf8g = Xf8 + (size_t)N * D;                       // H*16*4*4096 B
  unsigned short* Opart = (unsigned short*)(Qf8g + (size_t)H * 16 * 4 * 4096);
  float* Lsum = (float*)(Opart + (size_t)H * 2 * N * D);           // H*2*N fp32

  prep_kernel<<<dim3(16 + 2 * H), 256, 0, stream>>>(X, W, V, Xb, XbT, Xf8, Wt, Vt);
  qprep_kernel<<<dim3(16 * H), 256, 0, stream>>>(Xb, Wt, Qf8g);
  attn_kernel<<<dim3(NT * 2 * H), 256, 0, stream>>>(Qf8g, Xf8, XbT, Vt, Opart, Lsum);
  reduce_kernel<<<dim3(N * D / 4 / 256), 256, 0, stream>>>(Opart, Lsum, out);
}

// Round 14
// 191.543 us; speedup vs baseline: 1.0456x; 1.0210x over previous
//
#include <hip/hip_runtime.h>
#include <hip/hip_bf16.h>
#include <stdint.h>

#define N 2048
#define D 128
#define H 40
#define NT 16  // 64-key tiles per k-half

typedef __attribute__((ext_vector_type(8))) short short8;
typedef __attribute__((ext_vector_type(2))) float float2v;
typedef __attribute__((ext_vector_type(4))) float float4v;
typedef __attribute__((ext_vector_type(16))) float float16v;
typedef __attribute__((ext_vector_type(2))) _Float16 half2v;

static __device__ __forceinline__ unsigned short f32_to_bf16(float f) {
  unsigned int u = __builtin_bit_cast(unsigned int, f);
  unsigned int rounding = 0x7FFFu + ((u >> 16) & 1u);
  return (unsigned short)((u + rounding) >> 16);
}

static __device__ __forceinline__ unsigned int pk2(float lo, float hi) {
  return (unsigned int)f32_to_bf16(lo) | ((unsigned int)f32_to_bf16(hi) << 16);
}

// Fast pack: round-half-up + v_perm_b32 byte gather (3 VALU). Hot path only.
static __device__ __forceinline__ unsigned int pk2f(float lo, float hi) {
  unsigned int a = __builtin_bit_cast(unsigned int, lo) + 0x8000u;
  unsigned int b = __builtin_bit_cast(unsigned int, hi) + 0x8000u;
  return __builtin_amdgcn_perm(b, a, 0x07060302u);
}

static __device__ __forceinline__ unsigned long long pack4(float x0, float x1,
                                                           float x2, float x3) {
  return (unsigned long long)pk2(x0, x1) | ((unsigned long long)pk2(x2, x3) << 32);
}

static __device__ __forceinline__ float fast_exp2(float x) {
#if __has_builtin(__builtin_amdgcn_exp2f)
  return __builtin_amdgcn_exp2f(x);
#else
  return __expf(0.69314718056f * x);
#endif
}

static __device__ __forceinline__ float bf2f(unsigned short u) {
  unsigned int x = ((unsigned int)u) << 16;
  return __builtin_bit_cast(float, x);
}

static __device__ __forceinline__ long long mk64(unsigned int lo, unsigned int hi) {
  return (long long)(((unsigned long long)hi << 32) | lo);
}

static __device__ __forceinline__ void load_lds16(const void* g, void* l) {
  __builtin_amdgcn_global_load_lds(
      (const __attribute__((address_space(1))) unsigned int*)g,
      (__attribute__((address_space(3))) unsigned int*)l, 16, 0, 0);
}

#define MFMA32(a, b, c) __builtin_amdgcn_mfma_f32_32x32x16_bf16((a), (b), (c), 0, 0, 0)
#define MFMA8(a, b, c) __builtin_amdgcn_mfma_f32_32x32x16_fp8_fp8((a), (b), (c), 0, 0, 0)

// 32x32 C-layout regs -> two bf16 B-fragments (verified R3-R13).
static __device__ __forceinline__ void regs_to_bfrags(const float16v c, int hh,
                                                      short8& f0, short8& f1) {
  unsigned int a0 = pk2f(c[0], c[1]),   a1 = pk2f(c[2], c[3]);
  unsigned int a2 = pk2f(c[4], c[5]),   a3 = pk2f(c[6], c[7]);
  unsigned int a4 = pk2f(c[8], c[9]),   a5 = pk2f(c[10], c[11]);
  unsigned int a6 = pk2f(c[12], c[13]), a7 = pk2f(c[14], c[15]);
  unsigned int x0 = __shfl_xor(hh ? a0 : a2, 32);
  unsigned int x1 = __shfl_xor(hh ? a1 : a3, 32);
  unsigned int x2 = __shfl_xor(hh ? a4 : a6, 32);
  unsigned int x3 = __shfl_xor(hh ? a5 : a7, 32);
  uint4 u0 = {hh ? x0 : a0, hh ? x1 : a1, hh ? a2 : x0, hh ? a3 : x1};
  uint4 u1 = {hh ? x2 : a4, hh ? x3 : a5, hh ? a6 : x2, hh ? a7 : x3};
  f0 = __builtin_bit_cast(short8, u0);
  f1 = __builtin_bit_cast(short8, u1);
}

// Byte-granularity version for fp8 e4m3 B-frags (Q scaled by 64). (Verified R10-R13.)
static __device__ __forceinline__ void regs_to_f8frags(const float16v c, int hh,
                                                       long long& f0, long long& f1) {
  const float s = 64.0f;
  int v0 = __builtin_amdgcn_cvt_pk_fp8_f32(c[0] * s, c[1] * s, 0, false);
  v0 = __builtin_amdgcn_cvt_pk_fp8_f32(c[2] * s, c[3] * s, v0, true);
  int v1 = __builtin_amdgcn_cvt_pk_fp8_f32(c[4] * s, c[5] * s, 0, false);
  v1 = __builtin_amdgcn_cvt_pk_fp8_f32(c[6] * s, c[7] * s, v1, true);
  int v2 = __builtin_amdgcn_cvt_pk_fp8_f32(c[8] * s, c[9] * s, 0, false);
  v2 = __builtin_amdgcn_cvt_pk_fp8_f32(c[10] * s, c[11] * s, v2, true);
  int v3 = __builtin_amdgcn_cvt_pk_fp8_f32(c[12] * s, c[13] * s, 0, false);
  v3 = __builtin_amdgcn_cvt_pk_fp8_f32(c[14] * s, c[15] * s, v3, true);
  int t0 = __shfl_xor(hh ? v0 : v1, 32);
  int t1 = __shfl_xor(hh ? v2 : v3, 32);
  f0 = hh ? mk64((unsigned)t0, (unsigned)v1) : mk64((unsigned)v0, (unsigned)t0);
  f1 = hh ? mk64((unsigned)t1, (unsigned)v3) : mk64((unsigned)v2, (unsigned)t1);
}

// exp2(s/64), row-sum, pack bf16 P-fragments. (Verified R10-R13.)
static __device__ __forceinline__ void regs_to_pfrags(const float16v s, int hh,
                                                      float& lsum, short8& f0,
                                                      short8& f1) {
  float e[16];
  float acc = 0.0f;
#pragma unroll
  for (int i = 0; i < 16; i++) { e[i] = fast_exp2(s[i] * 0.015625f); acc += e[i]; }
  lsum += acc;
  unsigned int a0 = pk2f(e[0], e[1]),   a1 = pk2f(e[2], e[3]);
  unsigned int a2 = pk2f(e[4], e[5]),   a3 = pk2f(e[6], e[7]);
  unsigned int a4 = pk2f(e[8], e[9]),   a5 = pk2f(e[10], e[11]);
  unsigned int a6 = pk2f(e[12], e[13]), a7 = pk2f(e[14], e[15]);
  unsigned int x0 = __shfl_xor(hh ? a0 : a2, 32);
  unsigned int x1 = __shfl_xor(hh ? a1 : a3, 32);
  unsigned int x2 = __shfl_xor(hh ? a4 : a6, 32);
  unsigned int x3 = __shfl_xor(hh ? a5 : a7, 32);
  uint4 u0 = {hh ? x0 : a0, hh ? x1 : a1, hh ? a2 : x0, hh ? a3 : x1};
  uint4 u1 = {hh ? x2 : a4, hh ? x3 : a5, hh ? a6 : x2, hh ? a7 : x3};
  f0 = __builtin_bit_cast(short8, u0);
  f1 = __builtin_bit_cast(short8, u1);
}

// ---- staging helpers, 4-wave blocks (verified R7-R13) ----
static __device__ __forceinline__ void stage_64x256(const char* gbase, size_t stride,
                                                    char* lds, int wave, int lane) {
#pragma unroll
  for (int i = 0; i < 4; i++) {
    int r = wave * 16 + i * 4 + (lane >> 4);
    int us = (lane & 15) ^ (r & 15);
    load_lds16(gbase + (size_t)r * stride + us * 16, lds + (wave * 16 + i * 4) * 256);
  }
}
// 128 bf16 rows x 128 B -> 64 macro-rows x 256 B, macro-swizzled.
static __device__ __forceinline__ void stage_128x128(const char* gbase, size_t stride,
                                                     int colOff, char* lds, int wave,
                                                     int lane) {
#pragma unroll
  for (int i = 0; i < 4; i++) {
    int m = wave * 16 + i * 4 + (lane >> 4);
    int u = (lane & 15) ^ (m & 15);
    int grow = 2 * m + (u >> 3);
    load_lds16(gbase + (size_t)grow * stride + colOff + (u & 7) * 16,
               lds + (wave * 16 + i * 4) * 256);
  }
}
// 64 fp8 key-rows x 128 B -> 32 macro-rows x 256 B (8 KB).
static __device__ __forceinline__ void stage_k8(const char* gbase, char* lds,
                                                int wave, int lane) {
#pragma unroll
  for (int i = 0; i < 2; i++) {
    int m = wave * 8 + i * 4 + (lane >> 4);
    int u = (lane & 15) ^ (m & 15);
    int grow = 2 * m + (u >> 3);
    load_lds16(gbase + (size_t)grow * 128 + (u & 7) * 16,
               lds + (wave * 8 + i * 4) * 256);
  }
}
static __device__ __forceinline__ short8 read_macro(const char* lds, int row, int kunit) {
  int m = row >> 1;
  int u = ((row & 1) << 3) | kunit;
  return *(const short8*)(lds + m * 256 + ((u ^ (m & 15)) * 16));
}

// ---- fused prep: 0..15 X-conv; 16..55 V-conv; 56..695 qprep (self-sufficient) ----
__global__ __launch_bounds__(256)
void prep_kernel(const float* __restrict__ X, const float* __restrict__ W,
                 const float* __restrict__ V, unsigned short* __restrict__ XbT,
                 unsigned char* __restrict__ Xf8, unsigned short* __restrict__ Vt,
                 unsigned char* __restrict__ Qf8g) {
  const int tid = threadIdx.x;
  const int bx = blockIdx.x;
  __shared__ __align__(16) char smem[34816];
  unsigned short* Lt = (unsigned short*)smem;  // X/V parts: [128][136] padded

  if (bx < 16) {
    // ---- X -> XbT (bf16 [d][n]) + Xf8 ([n][d-permuted] e4m3)
    const int n0 = bx * 128;
    for (int i = tid; i < 128 * 32; i += 256) {
      int row = i >> 5, c4 = (i & 31) * 4;
      float4v x = *(const float4v*)(X + (size_t)(n0 + row) * D + c4);
      *(unsigned long long*)(Lt + row * 136 + c4) = pack4(x.x, x.y, x.z, x.w);
    }
    __syncthreads();
    for (int i = tid; i < 128 * 16; i += 256) {
      int d = i >> 4, g = i & 15;
      short8 v;
#pragma unroll
      for (int j = 0; j < 8; j++) v[j] = (short)Lt[(g * 8 + j) * 136 + d];
      *(short8*)(XbT + (size_t)d * N + n0 + g * 8) = v;
    }
    // Xf8 chunk c=2t+o holds d[32t+8o..+8) ++ d[32t+16+8o..+8)
    for (int i = tid; i < 128 * 8; i += 256) {
      int row = i >> 3, c = i & 7, t = c >> 1, o8 = (c & 1) * 8;
      const unsigned short* lp = Lt + row * 136;
      int d0 = t * 32 + o8, d1 = t * 32 + 16 + o8;
      short8 xa = *(const short8*)(lp + d0);
      short8 xb = *(const short8*)(lp + d1);
      int w0 = __builtin_amdgcn_cvt_pk_fp8_f32(bf2f(xa[0]), bf2f(xa[1]), 0, false);
      w0 = __builtin_amdgcn_cvt_pk_fp8_f32(bf2f(xa[2]), bf2f(xa[3]), w0, true);
      int w1 = __builtin_amdgcn_cvt_pk_fp8_f32(bf2f(xa[4]), bf2f(xa[5]), 0, false);
      w1 = __builtin_amdgcn_cvt_pk_fp8_f32(bf2f(xa[6]), bf2f(xa[7]), w1, true);
      int w2 = __builtin_amdgcn_cvt_pk_fp8_f32(bf2f(xb[0]), bf2f(xb[1]), 0, false);
      w2 = __builtin_amdgcn_cvt_pk_fp8_f32(bf2f(xb[2]), bf2f(xb[3]), w2, true);
      int w3 = __builtin_amdgcn_cvt_pk_fp8_f32(bf2f(xb[4]), bf2f(xb[5]), 0, false);
      w3 = __builtin_amdgcn_cvt_pk_fp8_f32(bf2f(xb[6]), bf2f(xb[7]), w3, true);
      uint4 st = {(unsigned)w0, (unsigned)w1, (unsigned)w2, (unsigned)w3};
      *(uint4*)(Xf8 + (size_t)(n0 + row) * 128 + c * 16) = st;
    }
  } else if (bx < 56) {
    // ---- V -> Vt (bf16, transposed [e][d])
    const int h = bx - 16;
    const float* src = V + (size_t)h * D * D;
    unsigned short* dst = Vt + (size_t)h * D * D;
    for (int i = tid; i < 128 * 32; i += 256) {
      int d = i >> 5, e4 = (i & 31) * 4;
      float4v w = *(const float4v*)(src + d * D + e4);
      Lt[(e4 + 0) * 136 + d] = f32_to_bf16(w.x);
      Lt[(e4 + 1) * 136 + d] = f32_to_bf16(w.y);
      Lt[(e4 + 2) * 136 + d] = f32_to_bf16(w.z);
      Lt[(e4 + 3) * 136 + d] = f32_to_bf16(w.w);
    }
    __syncthreads();
    for (int i = tid; i < 128 * 16; i += 256) {
      int e = i >> 4, u = i & 15;
      *(uint4*)((char*)dst + (size_t)e * 256 + u * 16) =
          *(const uint4*)((const char*)Lt + (size_t)e * 272 + u * 16);
    }
  } else {
    // ---- qprep: self-sufficient (stages W fp32 itself; X A-frags from fp32)
    const int qb = bx - 56;
    const int h = qb >> 4;
    const int q0 = (qb & 15) << 7;
    const int wave = tid >> 6, lane = tid & 63;
    const int l = lane & 31, hh = lane >> 5;
    const float scale = 0.1275174313f;  // log2(e)/sqrt(128)

    // Stage Wt[h] (scaled bf16) into row-swizzled LDS: row e (256B), unit d>>3 ^ (e&15)
    const float* Wh = W + (size_t)h * D * D;
    for (int i = tid; i < 128 * 32; i += 256) {
      int d = i >> 5, e4 = (i & 31) * 4;
      float4v w = *(const float4v*)(Wh + d * D + e4);
      int ub = ((d >> 3) * 16);
      int db = (d & 7) * 2;
      *(unsigned short*)(smem + (e4 + 0) * 256 + (ub ^ (((e4 + 0) & 15) * 16)) + db) =
          f32_to_bf16(w.x * scale);
      *(unsigned short*)(smem + (e4 + 1) * 256 + (ub ^ (((e4 + 1) & 15) * 16)) + db) =
          f32_to_bf16(w.y * scale);
      *(unsigned short*)(smem + (e4 + 2) * 256 + (ub ^ (((e4 + 2) & 15) * 16)) + db) =
          f32_to_bf16(w.z * scale);
      *(unsigned short*)(smem + (e4 + 3) * 256 + (ub ^ (((e4 + 3) & 15) * 16)) + db) =
          f32_to_bf16(w.w * scale);
    }
    // X A-frags straight from fp32 global (row q0+wave*32+l)
    short8 xfr[8];
    const float* Xrow = X + (size_t)(q0 + wave * 32 + l) * D;
#pragma unroll
    for (int dk = 0; dk < 8; dk++) {
      float4v a = *(const float4v*)(Xrow + dk * 16 + hh * 8);
      float4v b = *(const float4v*)(Xrow + dk * 16 + hh * 8 + 4);
      uint4 u = {pk2(a.x, a.y), pk2(a.z, a.w), pk2(b.x, b.y), pk2(b.z, b.w)};
      xfr[dk] = __builtin_bit_cast(short8, u);
    }
    __syncthreads();

    float16v qa[4];
#pragma unroll
    for (int et = 0; et < 4; et++) qa[et] = (float16v)0.0f;
#pragma unroll
    for (int et = 0; et < 4; et++) {
      const int r = et * 32 + l;
#pragma unroll
      for (int dk = 0; dk < 8; dk++) {
        short8 wa = *(const short8*)(smem + r * 256 + (((2 * dk + hh) ^ (r & 15)) * 16));
        qa[et] = MFMA32(wa, xfr[dk], qa[et]);
      }
    }
    char* base = (char*)Qf8g + ((size_t)qb * 4 + wave) * 4096;
#pragma unroll
    for (int et = 0; et < 4; et++) {
      long long f0, f1;
      regs_to_f8frags(qa[et], hh, f0, f1);
      uint4 st = {(unsigned)(unsigned long long)f0,
                  (unsigned)((unsigned long long)f0 >> 32),
                  (unsigned)(unsigned long long)f1,
                  (unsigned)((unsigned long long)f1 >> 32)};
      *(uint4*)(base + et * 1024 + lane * 16) = st;
    }
  }
}

// ---- attention: R13 kernel unchanged (32 KB arena, fp8 S, 2 barriers/tile) ----
__global__ __launch_bounds__(256)
void attn_kernel(const unsigned char* __restrict__ Qf8g,
                 const unsigned char* __restrict__ Xf8,
                 const unsigned short* __restrict__ XbT,
                 const unsigned short* __restrict__ Vt,
                 unsigned short* __restrict__ Opart, float* __restrict__ Lsum) {
  __shared__ __align__(16) char smem[32768];
  char* Xbuf = smem;           // 16K: XbT tile / Vt half1 / out staging
  char* KA = smem + 16384;     // 8K: fp8 K dbuf A
  char* KB = smem + 24576;     // 8K: fp8 K dbuf B
  const int bx = blockIdx.x;
  const int kh = bx & 1;
  const int qt = (bx >> 1) & 15;
  const int q0 = qt << 7;
  const int h = bx >> 5;
  const int tid = threadIdx.x;
  const int wave = tid >> 6, lane = tid & 63;
  const int l = lane & 31, hh = lane >> 5;

  const char* Xf8B = (const char*)Xf8;
  const char* XbTB = (const char*)XbT;
  const char* VtB = (const char*)(Vt + (size_t)h * D * D);
  const int kbase = kh * (N / 2);

  stage_k8(Xf8B + (size_t)kbase * 128, KA, wave, lane);
  long long qf8[8];
  {
    const char* qp = (const char*)Qf8g + (((size_t)h * 16 + qt) * 4 + wave) * 4096;
#pragma unroll
    for (int i = 0; i < 4; i++) {
      uint4 v = *(const uint4*)(qp + i * 1024 + lane * 16);
      qf8[2 * i] = mk64(v.x, v.y);
      qf8[2 * i + 1] = mk64(v.z, v.w);
    }
  }
  float16v Tacc[4];
#pragma unroll
  for (int dt = 0; dt < 4; dt++) Tacc[dt] = (float16v)0.0f;
  float lsum = 0.0f;
  __syncthreads();

  for (int kt = 0; kt < NT; kt++) {
    const char* curK = (kt & 1) ? KB : KA;
    char* altK = (kt & 1) ? KA : KB;
    const int k0 = kbase + kt * 64;
    stage_128x128(XbTB, 4096, k0 * 2, Xbuf, wave, lane);
    if (kt + 1 < NT)
      stage_k8(Xf8B + (size_t)(k0 + 64) * 128, altK, wave, lane);
    float16v s0 = (float16v)0.0f, s1 = (float16v)0.0f;
    {
      const int m0 = l >> 1, r0 = (l & 1) << 3;
      const int m1 = (32 + l) >> 1;
#pragma unroll
      for (int t = 0; t < 4; t++) {
        int u0 = (r0 | (t * 2 + hh)) ^ (m0 & 15);
        int u1 = (r0 | (t * 2 + hh)) ^ (m1 & 15);
        uint4 w0 = *(const uint4*)(curK + m0 * 256 + u0 * 16);
        uint4 w1 = *(const uint4*)(curK + m1 * 256 + u1 * 16);
        s0 = MFMA8(mk64(w0.x, w0.y), qf8[2 * t], s0);
        s1 = MFMA8(mk64(w1.x, w1.y), qf8[2 * t], s1);
        s0 = MFMA8(mk64(w0.z, w0.w), qf8[2 * t + 1], s0);
        s1 = MFMA8(mk64(w1.z, w1.w), qf8[2 * t + 1], s1);
      }
    }
    short8 pf0[2], pf1[2];
    regs_to_pfrags(s0, hh, lsum, pf0[0], pf0[1]);
    regs_to_pfrags(s1, hh, lsum, pf1[0], pf1[1]);
    __syncthreads();
#pragma unroll
    for (int kk = 0; kk < 2; kk++)
#pragma unroll
      for (int dt = 0; dt < 4; dt++) {
        short8 xt0 = read_macro(Xbuf, dt * 32 + l, kk * 2 + hh);
        Tacc[dt] = MFMA32(xt0, pf0[kk], Tacc[dt]);
        short8 xt1 = read_macro(Xbuf, dt * 32 + l, 4 + kk * 2 + hh);
        Tacc[dt] = MFMA32(xt1, pf1[kk], Tacc[dt]);
      }
    __syncthreads();
  }

  float tot = lsum + __shfl_xor(lsum, 32);
  if (hh == 0) Lsum[(size_t)(h * 2 + kh) * N + q0 + wave * 32 + l] = tot;

  stage_64x256(VtB, 256, KA, wave, lane);
  stage_64x256(VtB + 64 * 256, 256, Xbuf, wave, lane);
  short8 tb[8];
#pragma unroll
  for (int dt = 0; dt < 4; dt++)
    regs_to_bfrags(Tacc[dt], hh, tb[2 * dt], tb[2 * dt + 1]);
  __syncthreads();

  float16v oacc[4];
#pragma unroll
  for (int et = 0; et < 4; et++) oacc[et] = (float16v)0.0f;
#pragma unroll
  for (int et = 0; et < 2; et++) {
    const int r = et * 32 + l;
#pragma unroll
    for (int dk = 0; dk < 8; dk++) {
      short8 va = *(const short8*)(KA + r * 256 + (((2 * dk + hh) ^ (r & 15)) * 16));
      oacc[et] = MFMA32(va, tb[dk], oacc[et]);
    }
  }
#pragma unroll
  for (int et = 2; et < 4; et++) {
    const int r = (et - 2) * 32 + l;
#pragma unroll
    for (int dk = 0; dk < 8; dk++) {
      short8 va = *(const short8*)(Xbuf + r * 256 + (((2 * dk + hh) ^ (r & 15)) * 16));
      oacc[et] = MFMA32(va, tb[dk], oacc[et]);
    }
  }

  unsigned short* Oph = Opart + (size_t)(h * 2 + kh) * N * D;
#pragma unroll
  for (int pass = 0; pass < 2; pass++) {
    __syncthreads();
    const int qrow = wave * 32 + l;
#pragma unroll
    for (int etL = 0; etL < 2; etL++) {
      int et = pass * 2 + etL;
#pragma unroll
      for (int g = 0; g < 4; g++) {
        int unit = etL * 8 + 2 * g + hh;
        float4v v;
        v.x = oacc[et][4 * g + 0];
        v.y = oacc[et][4 * g + 1];
        v.z = oacc[et][4 * g + 2];
        v.w = oacc[et][4 * g + 3];
        *(float4v*)(smem + qrow * 256 + ((unit ^ (qrow & 15)) * 16)) = v;
      }
    }
    __syncthreads();
#pragma unroll
    for (int i = 0; i < 8; i++) {
      int idx = i * 256 + tid;
      int qr = idx >> 4, up = idx & 15, u = up ^ (qr & 15);
      float4v v = *(const float4v*)(smem + qr * 256 + up * 16);
      auto h0 = __builtin_amdgcn_cvt_pkrtz(v.x, v.y);
      auto h1 = __builtin_amdgcn_cvt_pkrtz(v.z, v.w);
      uint2 st = {__builtin_bit_cast(unsigned int, h0),
                  __builtin_bit_cast(unsigned int, h1)};
      *(uint2*)(Oph + (size_t)(q0 + qr) * D + pass * 64 + u * 4) = st;
    }
  }
}

// ---- reduce: 512 blocks, float2/thread: out = sum_h (O[h,0]+O[h,1])/(l0+l1) ----
__global__ __launch_bounds__(256)
void reduce_kernel(const unsigned short* __restrict__ Opart,
                   const float* __restrict__ Lsum, float* __restrict__ out) {
  int idx = blockIdx.x * 256 + threadIdx.x;  // float2 unit, 131072 total
  int n = idx >> 6;
  const unsigned int* base = (const unsigned int*)Opart;
  float2v acc = (float2v)0.0f;
#pragma unroll 8
  for (int h = 0; h < H; h++) {
    float lt = Lsum[(size_t)(2 * h) * N + n] + Lsum[(size_t)(2 * h + 1) * N + n];
    float il = __builtin_amdgcn_rcpf(lt);
    unsigned int a = base[(size_t)(2 * h) * (N * D / 2) + idx];
    unsigned int b = base[(size_t)(2 * h + 1) * (N * D / 2) + idx];
    float2v fa = __builtin_convertvector(__builtin_bit_cast(half2v, a), float2v);
    float2v fb = __builtin_convertvector(__builtin_bit_cast(half2v, b), float2v);
    acc += (fa + fb) * il;
  }
  *(float2v*)(out + (size_t)idx * 2) = acc;
}

extern "C" void kernel_launch(void* const* d_in, const int* in_sizes, int n_in,
                              void* d_out, int out_size, void* d_ws, size_t ws_size,
                              hipStream_t stream) {
  const float* X = (const float*)d_in[0];
  const float* W = (const float*)d_in[1];
  const float* V = (const float*)d_in[2];
  float* out = (float*)d_out;

  unsigned short* XbT = (unsigned short*)d_ws;       // D*N bf16
  unsigned short* Vt = XbT + (size_t)N * D;          // H*D*D bf16
  unsigned char* Xf8 = (unsigned char*)(Vt + (size_t)H * D * D);   // N*D fp8 (perm)
  unsigned char* Qf8g = Xf8 + (size_t)N * D;                       // H*16*4*4096 B
  unsigned short* Opart = (unsigned short*)(Qf8g + (size_t)H * 16 * 4 * 4096);
  float* Lsum = (float*)(Opart + (size_t)H * 2 * N * D);           // H*2*N fp32

  prep_kernel<<<dim3(56 + 16 * H), 256, 0, stream>>>(X, W, V, XbT, Xf8, Vt, Qf8g);
  attn_kernel<<<dim3(NT * 2 * H), 256, 0, stream>>>(Qf8g, Xf8, XbT, Vt, Opart, Lsum);
  reduce_kernel<<<dim3(N * D / 2 / 256), 256, 0, stream>>>(Opart, Lsum, out);
}